// Round 1
// baseline (378.159 us; speedup 1.0000x reference)
//
#include <hip/hip_runtime.h>

// Problem constants
#define N_SEQ 2048
#define DMODEL 1024
#define NH 16
#define DH 64
#define CHUNK 64
#define NCHUNK (N_SEQ / CHUNK)   // 32

typedef float f32x4 __attribute__((ext_vector_type(4)));
typedef __bf16 bf16x8 __attribute__((ext_vector_type(8)));
typedef unsigned short u16x4 __attribute__((ext_vector_type(4)));
typedef unsigned short u16x8 __attribute__((ext_vector_type(8)));

static __device__ inline unsigned short f2b(float x) {
    unsigned int u = __builtin_bit_cast(unsigned int, x);
    unsigned int r = (u + 0x7fffu + ((u >> 16) & 1u)) >> 16;  // RNE
    return (unsigned short)r;
}

// ---------------------------------------------------------------- casts
__global__ __launch_bounds__(256) void cast_f32_bf16(const float* __restrict__ src,
                                                     unsigned short* __restrict__ dst, int n4) {
    int i = blockIdx.x * 256 + threadIdx.x;
    if (i >= n4) return;
    float4 v = reinterpret_cast<const float4*>(src)[i];
    u16x4 o;
    o[0] = f2b(v.x); o[1] = f2b(v.y); o[2] = f2b(v.z); o[3] = f2b(v.w);
    reinterpret_cast<u16x4*>(dst)[i] = o;
}

// ---------------------------------------------------------------- GEMM (bf16 MFMA, 128x128 tile)
// A: [M][K] bf16 (row-major), B: [N][K] bf16 (row = output column, i.e. weight layout W[out][in])
// MODE 0: scatter to QKV f32 [3][16][2048][64];  MODE 1: out[row*N+col] = acc + bias[col]
template<int MODE>
__global__ __launch_bounds__(256, 2) void gemm_bf16(
    const unsigned short* __restrict__ A,
    const unsigned short* __restrict__ B,
    float* __restrict__ out,
    const float* __restrict__ bias,
    int M, int N, int K)
{
    // slice-major LDS: [k-slice][row][8] -> 16B-aligned fragments, 2-way-max read conflicts
    __shared__ __align__(16) unsigned short As[4][128][8];
    __shared__ __align__(16) unsigned short Bs[4][128][8];

    const int t = threadIdx.x;
    const int bn = blockIdx.x, bm = blockIdx.y;
    const int wave = t >> 6, lane = t & 63;
    const int wm = wave >> 1, wn = wave & 1;
    const int r16 = lane & 15, ks = lane >> 4;

    f32x4 acc[4][4] = {};

    const unsigned short* gA = A + (size_t)bm * 128 * K;
    const unsigned short* gB = B + (size_t)bn * 128 * K;
    const int rS = t >> 2, sS = t & 3;

    for (int k0 = 0; k0 < K; k0 += 32) {
        __syncthreads();
        #pragma unroll
        for (int p = 0; p < 2; ++p) {
            int r = rS + p * 64;
            *reinterpret_cast<u16x8*>(&As[sS][r][0]) =
                *reinterpret_cast<const u16x8*>(&gA[(size_t)r * K + k0 + sS * 8]);
            *reinterpret_cast<u16x8*>(&Bs[sS][r][0]) =
                *reinterpret_cast<const u16x8*>(&gB[(size_t)r * K + k0 + sS * 8]);
        }
        __syncthreads();

        bf16x8 af[4], bf[4];
        #pragma unroll
        for (int m = 0; m < 4; ++m)
            af[m] = *reinterpret_cast<const bf16x8*>(&As[ks][wm * 64 + m * 16 + r16][0]);
        #pragma unroll
        for (int n = 0; n < 4; ++n)
            bf[n] = *reinterpret_cast<const bf16x8*>(&Bs[ks][wn * 64 + n * 16 + r16][0]);
        #pragma unroll
        for (int m = 0; m < 4; ++m)
            #pragma unroll
            for (int n = 0; n < 4; ++n)
                acc[m][n] = __builtin_amdgcn_mfma_f32_16x16x32_bf16(af[m], bf[n], acc[m][n], 0, 0, 0);
    }

    #pragma unroll
    for (int m = 0; m < 4; ++m) {
        int row0 = bm * 128 + wm * 64 + m * 16 + ks * 4;
        #pragma unroll
        for (int n = 0; n < 4; ++n) {
            int col = bn * 128 + wn * 64 + n * 16 + r16;
            if (MODE == 0) {
                int w = col >> 10, h = (col >> 6) & 15, d = col & 63;
                float* dst = out + (size_t)w * (NH * (size_t)N_SEQ * DH)
                                 + (size_t)h * N_SEQ * DH + d;
                #pragma unroll
                for (int j = 0; j < 4; ++j)
                    dst[(size_t)(row0 + j) * DH] = acc[m][n][j];
            } else {
                float bv = bias[col];
                #pragma unroll
                for (int j = 0; j < 4; ++j)
                    out[(size_t)(row0 + j) * N + col] = acc[m][n][j] + bv;
            }
        }
    }
}

// ---------------------------------------------------------------- per-head max L2 norm of q / k
__global__ __launch_bounds__(256) void head_norms(const float* __restrict__ QK,
                                                  float* __restrict__ norms) {
    const int h = blockIdx.x & 15;
    const int which = blockIdx.x >> 4;              // 0 = q, 1 = k
    const float* base = QK + (size_t)which * (NH * (size_t)N_SEQ * DH) + (size_t)h * N_SEQ * DH;
    const int t = threadIdx.x, wave = t >> 6, lane = t & 63;
    float mx = 0.f;
    for (int i = wave; i < N_SEQ; i += 4) {
        float x = base[(size_t)i * DH + lane];
        float s = x * x;
        #pragma unroll
        for (int off = 1; off < 64; off <<= 1) s += __shfl_xor(s, off);
        mx = fmaxf(mx, s);
    }
    __shared__ float red[4];
    if (lane == 0) red[wave] = mx;
    __syncthreads();
    if (t == 0) {
        float m = fmaxf(fmaxf(red[0], red[1]), fmaxf(red[2], red[3]));
        norms[which * 16 + h] = sqrtf(m);
    }
}

// ---------------------------------------------------------------- per-chunk sums: S = K^T V, z = sum k, vs = sum v
__global__ __launch_bounds__(256) void chunk_sums(const float* __restrict__ Kf,
                                                  const float* __restrict__ Vf,
                                                  float* __restrict__ Ssum,
                                                  float* __restrict__ zsum,
                                                  float* __restrict__ vssum) {
    const int h = blockIdx.x >> 5;
    const int c = blockIdx.x & 31;
    __shared__ __align__(16) float Kl[CHUNK][DH];
    __shared__ __align__(16) float Vl[CHUNK][DH];
    const size_t off = ((size_t)h * N_SEQ + c * CHUNK) * DH;
    const int t = threadIdx.x;
    #pragma unroll
    for (int i2 = 0; i2 < 4; ++i2) {
        int idx = t + i2 * 256;
        reinterpret_cast<float4*>(&Kl[0][0])[idx] = reinterpret_cast<const float4*>(Kf + off)[idx];
        reinterpret_cast<float4*>(&Vl[0][0])[idx] = reinterpret_cast<const float4*>(Vf + off)[idx];
    }
    __syncthreads();

    const int d1b = (t >> 4) * 4;
    const int d2b = (t & 15) * 4;
    float s[4][4] = {};
    for (int j = 0; j < CHUNK; ++j) {
        float kv[4], vv[4];
        #pragma unroll
        for (int a = 0; a < 4; ++a) kv[a] = Kl[j][d1b + a];
        #pragma unroll
        for (int b = 0; b < 4; ++b) vv[b] = Vl[j][d2b + b];
        #pragma unroll
        for (int a = 0; a < 4; ++a)
            #pragma unroll
            for (int b = 0; b < 4; ++b) s[a][b] += kv[a] * vv[b];
    }
    float* Sout = Ssum + (size_t)blockIdx.x * (DH * DH);
    #pragma unroll
    for (int a = 0; a < 4; ++a)
        #pragma unroll
        for (int b = 0; b < 4; ++b)
            Sout[(size_t)(d1b + a) * DH + d2b + b] = s[a][b];

    if (t < 64) {
        float z = 0.f;
        for (int j = 0; j < CHUNK; ++j) z += Kl[j][t];
        zsum[(size_t)blockIdx.x * DH + t] = z;
    } else if (t < 128) {
        int d = t - 64;
        float z = 0.f;
        for (int j = 0; j < CHUNK; ++j) z += Vl[j][d];
        vssum[(size_t)blockIdx.x * DH + d] = z;
    }
}

// ---------------------------------------------------------------- exclusive scan over chunks (per head)
__global__ __launch_bounds__(256) void chunk_scan(float* __restrict__ Ssum,
                                                  float* __restrict__ zsum,
                                                  float* __restrict__ vssum) {
    const int h = blockIdx.x;
    for (int e = threadIdx.x; e < DH * DH; e += 256) {
        float run = 0.f;
        for (int c = 0; c < NCHUNK; ++c) {
            size_t idx = ((size_t)(h * NCHUNK + c)) * (DH * DH) + e;
            float tmp = Ssum[idx]; Ssum[idx] = run; run += tmp;
        }
    }
    if (threadIdx.x < 64) {
        int e = threadIdx.x;
        float run = 0.f;
        for (int c = 0; c < NCHUNK; ++c) {
            size_t idx = (size_t)(h * NCHUNK + c) * DH + e;
            float tmp = zsum[idx]; zsum[idx] = run; run += tmp;
        }
    } else if (threadIdx.x < 128) {
        int e = threadIdx.x - 64;
        float run = 0.f;
        for (int c = 0; c < NCHUNK; ++c) {
            size_t idx = (size_t)(h * NCHUNK + c) * DH + e;
            float tmp = vssum[idx]; vssum[idx] = run; run += tmp;
        }
    }
}

// ---------------------------------------------------------------- intra-chunk causal attention + combine
__global__ __launch_bounds__(256) void intra_attn(
    const float* __restrict__ Qf, const float* __restrict__ Kf, const float* __restrict__ Vf,
    const float* __restrict__ Ssum, const float* __restrict__ zsum, const float* __restrict__ vssum,
    const float* __restrict__ norms, unsigned short* __restrict__ vhb) {
    const int h = blockIdx.x >> 5;
    const int c = blockIdx.x & 31;
    __shared__ __align__(16) float Ql[CHUNK][DH + 4];  // +4 pad: avoid 16-way row conflict
    __shared__ __align__(16) float Kl[CHUNK][DH];
    __shared__ __align__(16) float Vl[CHUNK][DH];
    __shared__ float zp[DH], vsp[DH];

    const size_t off = ((size_t)h * N_SEQ + c * CHUNK) * DH;
    const int t = threadIdx.x;
    #pragma unroll
    for (int i2 = 0; i2 < 4; ++i2) {
        int idx = t + i2 * 256;
        int r = idx >> 4, dc = (idx & 15) * 4;
        *reinterpret_cast<float4*>(&Ql[r][dc]) = reinterpret_cast<const float4*>(Qf + off)[idx];
        reinterpret_cast<float4*>(&Kl[0][0])[idx] = reinterpret_cast<const float4*>(Kf + off)[idx];
        reinterpret_cast<float4*>(&Vl[0][0])[idx] = reinterpret_cast<const float4*>(Vf + off)[idx];
    }
    if (t < 64) zp[t] = zsum[(size_t)blockIdx.x * DH + t];
    else if (t < 128) vsp[t - 64] = vssum[(size_t)blockIdx.x * DH + (t - 64)];
    __syncthreads();

    const float alpha = 1.f / (norms[h] * norms[16 + h]);
    const int i = t >> 2;        // row in chunk
    const int p = t & 3;         // quarter (d-range for dots, e-range for outputs)
    const int e0 = p * 16;

    float qp[16];
    #pragma unroll
    for (int a = 0; a < 16; ++a) qp[a] = Ql[i][e0 + a];

    // den init: global position + alpha * q . z_prev
    float dpart = 0.f;
    #pragma unroll
    for (int a = 0; a < 16; ++a) dpart += qp[a] * zp[e0 + a];
    dpart += __shfl_xor(dpart, 1);
    dpart += __shfl_xor(dpart, 2);
    float den = (float)(c * CHUNK) + alpha * dpart;

    // num init: vs_prev + alpha * q^T S_prev   (S_prev read from global, 16-lane broadcast)
    float num[16];
    #pragma unroll
    for (int eo = 0; eo < 16; ++eo) num[eo] = 0.f;
    const float* Sg = Ssum + (size_t)blockIdx.x * (DH * DH) + e0;
    for (int d = 0; d < DH; ++d) {
        float qd = Ql[i][d];
        #pragma unroll
        for (int eo = 0; eo < 16; ++eo) num[eo] += qd * Sg[(size_t)d * DH + eo];
    }
    #pragma unroll
    for (int eo = 0; eo < 16; ++eo) num[eo] = vsp[e0 + eo] + alpha * num[eo];

    // intra-chunk causal loop (inclusive)
    for (int j = 0; j <= i; ++j) {
        float dp = 0.f;
        #pragma unroll
        for (int a = 0; a < 16; ++a) dp += qp[a] * Kl[j][e0 + a];
        dp += __shfl_xor(dp, 1);
        dp += __shfl_xor(dp, 2);
        float s = 1.f + alpha * dp;
        den += s;
        #pragma unroll
        for (int eo = 0; eo < 16; ++eo) num[eo] += s * Vl[j][e0 + eo];
    }

    const float invd = 1.f / den;
    u16x8 o0, o1;
    #pragma unroll
    for (int eo = 0; eo < 8; ++eo) o0[eo] = f2b(num[eo] * invd);
    #pragma unroll
    for (int eo = 0; eo < 8; ++eo) o1[eo] = f2b(num[8 + eo] * invd);
    unsigned short* op = vhb + (size_t)(c * CHUNK + i) * (NH * DH) + h * DH + e0;
    *reinterpret_cast<u16x8*>(op) = o0;
    *(reinterpret_cast<u16x8*>(op) + 1) = o1;
}

// ---------------------------------------------------------------- launch
extern "C" void kernel_launch(void* const* d_in, const int* in_sizes, int n_in,
                              void* d_out, int out_size, void* d_ws, size_t ws_size,
                              hipStream_t stream) {
    const float* X  = (const float*)d_in[0];
    const float* Wq = (const float*)d_in[1];
    const float* Wk = (const float*)d_in[2];
    const float* Wv = (const float*)d_in[3];
    const float* Wo = (const float*)d_in[4];
    const float* bo = (const float*)d_in[5];
    float* out = (float*)d_out;

    char* w = (char*)d_ws;
    unsigned short* Xb   = (unsigned short*)(w);                    // 4 MiB  [2048][1024]
    unsigned short* Wb   = (unsigned short*)(w + (4u  << 20));      // 6 MiB  [3072][1024]
    unsigned short* Wob  = (unsigned short*)(w + (10u << 20));      // 2 MiB  [1024][1024]
    float*          Qf   = (float*)(w + (12u << 20));               // 8 MiB  [16][2048][64]
    float*          Kf   = (float*)(w + (20u << 20));               // 8 MiB
    float*          Vf   = (float*)(w + (28u << 20));               // 8 MiB
    unsigned short* vhb  = (unsigned short*)(w + (36u << 20));      // 4 MiB  [2048][1024]
    float*          norms= (float*)(w + (40u << 20));               // 128 B
    float*          Ssum = (float*)(w + (41u << 20));               // 8 MiB  [512][64][64]
    float*          zsum = (float*)(w + (49u << 20));               // 128 KiB
    float*          vssum= (float*)(w + (49u << 20) + (1u << 18));  // 128 KiB

    cast_f32_bf16<<<2048, 256, 0, stream>>>(X,  Xb, 524288);
    cast_f32_bf16<<<1024, 256, 0, stream>>>(Wq, Wb,                262144);
    cast_f32_bf16<<<1024, 256, 0, stream>>>(Wk, Wb + (1u << 20),   262144);
    cast_f32_bf16<<<1024, 256, 0, stream>>>(Wv, Wb + (2u << 20),   262144);
    cast_f32_bf16<<<1024, 256, 0, stream>>>(Wo, Wob,               262144);

    gemm_bf16<0><<<dim3(24, 16), 256, 0, stream>>>(Xb, Wb, Qf, nullptr, 2048, 3072, 1024);
    head_norms<<<32, 256, 0, stream>>>(Qf, norms);
    chunk_sums<<<512, 256, 0, stream>>>(Kf, Vf, Ssum, zsum, vssum);
    chunk_scan<<<16, 256, 0, stream>>>(Ssum, zsum, vssum);
    intra_attn<<<512, 256, 0, stream>>>(Qf, Kf, Vf, Ssum, zsum, vssum, norms, vhb);
    gemm_bf16<1><<<dim3(8, 16), 256, 0, stream>>>(vhb, Wob, out, bo, 2048, 1024, 1024);
}

// Round 2
// 131.612 us; speedup vs baseline: 2.8733x; 2.8733x over previous
//
#include <hip/hip_runtime.h>

// Problem constants
#define N_SEQ 2048
#define DMODEL 1024
#define NH 16
#define DH 64
#define CHUNK 64
#define NCHUNK (N_SEQ / CHUNK)   // 32

typedef float f32x4 __attribute__((ext_vector_type(4)));
typedef __bf16 bf16x8 __attribute__((ext_vector_type(8)));
typedef unsigned short u16x4 __attribute__((ext_vector_type(4)));
typedef unsigned short u16x8 __attribute__((ext_vector_type(8)));

static __device__ inline unsigned short f2b(float x) {
    unsigned int u = __builtin_bit_cast(unsigned int, x);
    unsigned int r = (u + 0x7fffu + ((u >> 16) & 1u)) >> 16;  // RNE
    return (unsigned short)r;
}

// async global -> LDS, 16B per lane; LDS dest is wave-uniform base + lane*16
static __device__ inline void gload_lds16(const unsigned short* g, unsigned short* l) {
    __builtin_amdgcn_global_load_lds(
        (const __attribute__((address_space(1))) unsigned int*)g,
        (__attribute__((address_space(3))) unsigned int*)l, 16, 0, 0);
}

// ---------------------------------------------------------------- casts
__global__ __launch_bounds__(256) void cast_f32_bf16(const float* __restrict__ src,
                                                     unsigned short* __restrict__ dst, int n4) {
    int i = blockIdx.x * 256 + threadIdx.x;
    if (i >= n4) return;
    float4 v = reinterpret_cast<const float4*>(src)[i];
    u16x4 o;
    o[0] = f2b(v.x); o[1] = f2b(v.y); o[2] = f2b(v.z); o[3] = f2b(v.w);
    reinterpret_cast<u16x4*>(dst)[i] = o;
}

// ---------------------------------------------------------------- GEMM (bf16 MFMA, 128x128 tile, global_load_lds staging)
// A: [M][K] bf16 (row-major), B: [N][K] bf16 (row = output column, i.e. weight layout W[out][in])
// MODE 0: scatter to QKV f32 [3][16][2048][64];  MODE 1: out[row*N+col] = acc + bias[col]
template<int MODE>
__global__ __launch_bounds__(256, 2) void gemm_bf16(
    const unsigned short* __restrict__ A,
    const unsigned short* __restrict__ B,
    float* __restrict__ out,
    const float* __restrict__ bias,
    int M, int N, int K)
{
    __shared__ __align__(16) unsigned short As[128][32];   // linear row-major: gload_lds-compatible
    __shared__ __align__(16) unsigned short Bs[128][32];

    const int t = threadIdx.x;
    const int bn = blockIdx.x, bm = blockIdx.y;
    const int wave = t >> 6, lane = t & 63;
    const int wm = wave >> 1, wn = wave & 1;
    const int r16 = lane & 15, ks = lane >> 4;

    f32x4 acc[4][4] = {};

    const unsigned short* gA = A + (size_t)bm * 128 * K;
    const unsigned short* gB = B + (size_t)bn * 128 * K;
    const int lrow = lane >> 2;          // 0..15 row within 16-row chunk
    const int lcol = (lane & 3) * 8;     // elem col within 32

    for (int k0 = 0; k0 < K; k0 += 32) {
        __syncthreads();
        #pragma unroll
        for (int p = 0; p < 2; ++p) {
            int row = p * 64 + wave * 16;
            gload_lds16(&gA[(size_t)(row + lrow) * K + k0 + lcol], &As[row][0]);
            gload_lds16(&gB[(size_t)(row + lrow) * K + k0 + lcol], &Bs[row][0]);
        }
        __syncthreads();   // compiler inserts vmcnt(0) drain here

        bf16x8 af[4], bfr[4];
        #pragma unroll
        for (int m = 0; m < 4; ++m)
            af[m] = *reinterpret_cast<const bf16x8*>(&As[wm * 64 + m * 16 + r16][ks * 8]);
        #pragma unroll
        for (int n = 0; n < 4; ++n)
            bfr[n] = *reinterpret_cast<const bf16x8*>(&Bs[wn * 64 + n * 16 + r16][ks * 8]);
        #pragma unroll
        for (int m = 0; m < 4; ++m)
            #pragma unroll
            for (int n = 0; n < 4; ++n)
                acc[m][n] = __builtin_amdgcn_mfma_f32_16x16x32_bf16(af[m], bfr[n], acc[m][n], 0, 0, 0);
    }

    #pragma unroll
    for (int m = 0; m < 4; ++m) {
        int row0 = bm * 128 + wm * 64 + m * 16 + ks * 4;
        #pragma unroll
        for (int n = 0; n < 4; ++n) {
            int col = bn * 128 + wn * 64 + n * 16 + r16;
            if (MODE == 0) {
                int w = col >> 10, h = (col >> 6) & 15, d = col & 63;
                float* dst = out + (size_t)w * (NH * (size_t)N_SEQ * DH)
                                 + (size_t)h * N_SEQ * DH + d;
                #pragma unroll
                for (int j = 0; j < 4; ++j)
                    dst[(size_t)(row0 + j) * DH] = acc[m][n][j];
            } else {
                float bv = bias[col];
                #pragma unroll
                for (int j = 0; j < 4; ++j)
                    out[(size_t)(row0 + j) * N + col] = acc[m][n][j] + bv;
            }
        }
    }
}

// ---------------------------------------------------------------- per-head max L2 norm, stage 1
// grid 256 = which(2) x head(16) x rowchunk(8); one thread per row, no per-row shuffle chain
__global__ __launch_bounds__(256) void norms1(const float* __restrict__ QK,
                                              float* __restrict__ partial) {
    const int b = blockIdx.x;
    const int rc = b & 7, h = (b >> 3) & 15, which = b >> 7;
    const float* base = QK + ((size_t)which * NH + h) * N_SEQ * DH + (size_t)rc * 256 * DH;
    const int t = threadIdx.x;
    const float4* rp = reinterpret_cast<const float4*>(base + (size_t)t * DH);
    float s = 0.f;
    #pragma unroll
    for (int j = 0; j < 16; ++j) {
        float4 v = rp[j];
        s += v.x * v.x + v.y * v.y + v.z * v.z + v.w * v.w;
    }
    #pragma unroll
    for (int off = 1; off < 64; off <<= 1) s = fmaxf(s, __shfl_xor(s, off));
    __shared__ float red[4];
    if ((t & 63) == 0) red[t >> 6] = s;
    __syncthreads();
    if (t == 0) partial[b] = fmaxf(fmaxf(red[0], red[1]), fmaxf(red[2], red[3]));
}

__global__ __launch_bounds__(64) void norms2(const float* __restrict__ partial,
                                             float* __restrict__ norms) {
    int t = threadIdx.x;
    if (t < 32) {
        float m = 0.f;
        #pragma unroll
        for (int j = 0; j < 8; ++j) m = fmaxf(m, partial[t * 8 + j]);
        norms[t] = sqrtf(m);
    }
}

// ---------------------------------------------------------------- per-chunk sums: S = K^T V, z = sum k, vs = sum v
__global__ __launch_bounds__(256) void chunk_sums(const float* __restrict__ Kf,
                                                  const float* __restrict__ Vf,
                                                  float* __restrict__ Ssum,
                                                  float* __restrict__ zsum,
                                                  float* __restrict__ vssum) {
    const int h = blockIdx.x >> 5;
    const int c = blockIdx.x & 31;
    __shared__ __align__(16) float Kl[CHUNK][DH];
    __shared__ __align__(16) float Vl[CHUNK][DH];
    const size_t off = ((size_t)h * N_SEQ + c * CHUNK) * DH;
    const int t = threadIdx.x;
    #pragma unroll
    for (int i2 = 0; i2 < 4; ++i2) {
        int idx = t + i2 * 256;
        reinterpret_cast<float4*>(&Kl[0][0])[idx] = reinterpret_cast<const float4*>(Kf + off)[idx];
        reinterpret_cast<float4*>(&Vl[0][0])[idx] = reinterpret_cast<const float4*>(Vf + off)[idx];
    }
    __syncthreads();

    const int d1b = (t >> 4) * 4;
    const int d2b = (t & 15) * 4;
    float s[4][4] = {};
    for (int j = 0; j < CHUNK; ++j) {
        float kv[4], vv[4];
        #pragma unroll
        for (int a = 0; a < 4; ++a) kv[a] = Kl[j][d1b + a];
        #pragma unroll
        for (int b = 0; b < 4; ++b) vv[b] = Vl[j][d2b + b];
        #pragma unroll
        for (int a = 0; a < 4; ++a)
            #pragma unroll
            for (int b = 0; b < 4; ++b) s[a][b] += kv[a] * vv[b];
    }
    float* Sout = Ssum + (size_t)blockIdx.x * (DH * DH);
    #pragma unroll
    for (int a = 0; a < 4; ++a)
        #pragma unroll
        for (int b = 0; b < 4; ++b)
            Sout[(size_t)(d1b + a) * DH + d2b + b] = s[a][b];

    if (t < 64) {
        float z = 0.f;
        for (int j = 0; j < CHUNK; ++j) z += Kl[j][t];
        zsum[(size_t)blockIdx.x * DH + t] = z;
    } else if (t < 128) {
        int d = t - 64;
        float z = 0.f;
        for (int j = 0; j < CHUNK; ++j) z += Vl[j][d];
        vssum[(size_t)blockIdx.x * DH + d] = z;
    }
}

// ---------------------------------------------------------------- exclusive scan over chunks (parallel over elements)
// blocks 0..255: Ssum (16 heads x 16 blocks x 256 threads = one thread per S element)
// blocks 256..263: zsum + vssum (2 arrays x 16 heads x 64 elems = 2048 scans)
__global__ __launch_bounds__(256) void chunk_scan(float* __restrict__ Ssum,
                                                  float* __restrict__ zsum,
                                                  float* __restrict__ vssum) {
    const int b = blockIdx.x;
    if (b < 256) {
        const int h = b >> 4;
        const int e = (b & 15) * 256 + threadIdx.x;     // 0..4095
        size_t base = (size_t)h * NCHUNK * (DH * DH) + e;
        float run = 0.f;
        for (int c = 0; c < NCHUNK; ++c) {
            size_t idx = base + (size_t)c * (DH * DH);
            float tmp = Ssum[idx]; Ssum[idx] = run; run += tmp;
        }
    } else {
        const int g = (b - 256) * 256 + threadIdx.x;    // 0..2047
        const int which = g >> 10, h = (g >> 6) & 15, e = g & 63;
        float* arr = which ? vssum : zsum;
        size_t base = (size_t)h * NCHUNK * DH + e;
        float run = 0.f;
        for (int c = 0; c < NCHUNK; ++c) {
            size_t idx = base + (size_t)c * DH;
            float tmp = arr[idx]; arr[idx] = run; run += tmp;
        }
    }
}

// ---------------------------------------------------------------- intra-chunk causal attention + combine
__global__ __launch_bounds__(256) void intra_attn(
    const float* __restrict__ Qf, const float* __restrict__ Kf, const float* __restrict__ Vf,
    const float* __restrict__ Ssum, const float* __restrict__ zsum, const float* __restrict__ vssum,
    const float* __restrict__ norms, unsigned short* __restrict__ vhb) {
    const int h = blockIdx.x >> 5;
    const int c = blockIdx.x & 31;
    __shared__ __align__(16) float Ql[CHUNK][DH + 4];  // +4 pad: avoid 16-way row conflict
    __shared__ __align__(16) float Kl[CHUNK][DH];
    __shared__ __align__(16) float Vl[CHUNK][DH];
    __shared__ float zp[DH], vsp[DH];

    const size_t off = ((size_t)h * N_SEQ + c * CHUNK) * DH;
    const int t = threadIdx.x;
    #pragma unroll
    for (int i2 = 0; i2 < 4; ++i2) {
        int idx = t + i2 * 256;
        int r = idx >> 4, dc = (idx & 15) * 4;
        *reinterpret_cast<float4*>(&Ql[r][dc]) = reinterpret_cast<const float4*>(Qf + off)[idx];
        reinterpret_cast<float4*>(&Kl[0][0])[idx] = reinterpret_cast<const float4*>(Kf + off)[idx];
        reinterpret_cast<float4*>(&Vl[0][0])[idx] = reinterpret_cast<const float4*>(Vf + off)[idx];
    }
    if (t < 64) zp[t] = zsum[(size_t)blockIdx.x * DH + t];
    else if (t < 128) vsp[t - 64] = vssum[(size_t)blockIdx.x * DH + (t - 64)];
    __syncthreads();

    const float alpha = 1.f / (norms[h] * norms[16 + h]);
    const int i = t >> 2;        // row in chunk
    const int p = t & 3;         // quarter (d-range for dots, e-range for outputs)
    const int e0 = p * 16;

    float qp[16];
    #pragma unroll
    for (int a = 0; a < 16; ++a) qp[a] = Ql[i][e0 + a];

    // den init: global position + alpha * q . z_prev
    float dpart = 0.f;
    #pragma unroll
    for (int a = 0; a < 16; ++a) dpart += qp[a] * zp[e0 + a];
    dpart += __shfl_xor(dpart, 1);
    dpart += __shfl_xor(dpart, 2);
    float den = (float)(c * CHUNK) + alpha * dpart;

    // num init: vs_prev + alpha * q^T S_prev   (S_prev read from global, 16-lane broadcast)
    float num[16];
    #pragma unroll
    for (int eo = 0; eo < 16; ++eo) num[eo] = 0.f;
    const float* Sg = Ssum + (size_t)blockIdx.x * (DH * DH) + e0;
    for (int d = 0; d < DH; ++d) {
        float qd = Ql[i][d];
        #pragma unroll
        for (int eo = 0; eo < 16; ++eo) num[eo] += qd * Sg[(size_t)d * DH + eo];
    }
    #pragma unroll
    for (int eo = 0; eo < 16; ++eo) num[eo] = vsp[e0 + eo] + alpha * num[eo];

    // intra-chunk causal loop (inclusive)
    for (int j = 0; j <= i; ++j) {
        float dp = 0.f;
        #pragma unroll
        for (int a = 0; a < 16; ++a) dp += qp[a] * Kl[j][e0 + a];
        dp += __shfl_xor(dp, 1);
        dp += __shfl_xor(dp, 2);
        float s = 1.f + alpha * dp;
        den += s;
        #pragma unroll
        for (int eo = 0; eo < 16; ++eo) num[eo] += s * Vl[j][e0 + eo];
    }

    const float invd = 1.f / den;
    u16x8 o0, o1;
    #pragma unroll
    for (int eo = 0; eo < 8; ++eo) o0[eo] = f2b(num[eo] * invd);
    #pragma unroll
    for (int eo = 0; eo < 8; ++eo) o1[eo] = f2b(num[8 + eo] * invd);
    unsigned short* op = vhb + (size_t)(c * CHUNK + i) * (NH * DH) + h * DH + e0;
    *reinterpret_cast<u16x8*>(op) = o0;
    *(reinterpret_cast<u16x8*>(op) + 1) = o1;
}

// ---------------------------------------------------------------- launch
extern "C" void kernel_launch(void* const* d_in, const int* in_sizes, int n_in,
                              void* d_out, int out_size, void* d_ws, size_t ws_size,
                              hipStream_t stream) {
    const float* X  = (const float*)d_in[0];
    const float* Wq = (const float*)d_in[1];
    const float* Wk = (const float*)d_in[2];
    const float* Wv = (const float*)d_in[3];
    const float* Wo = (const float*)d_in[4];
    const float* bo = (const float*)d_in[5];
    float* out = (float*)d_out;

    char* w = (char*)d_ws;
    unsigned short* Xb   = (unsigned short*)(w);                    // 4 MiB  [2048][1024]
    unsigned short* Wb   = (unsigned short*)(w + (4u  << 20));      // 6 MiB  [3072][1024]
    unsigned short* Wob  = (unsigned short*)(w + (10u << 20));      // 2 MiB  [1024][1024]
    float*          Qf   = (float*)(w + (12u << 20));               // 8 MiB  [16][2048][64]
    float*          Kf   = (float*)(w + (20u << 20));               // 8 MiB
    float*          Vf   = (float*)(w + (28u << 20));               // 8 MiB
    unsigned short* vhb  = (unsigned short*)(w + (36u << 20));      // 4 MiB  [2048][1024]
    float*          norms= (float*)(w + (40u << 20));               // 32 floats
    float*          partial = norms + 64;                           // 256 floats
    float*          Ssum = (float*)(w + (41u << 20));               // 8 MiB  [512][64][64]
    float*          zsum = (float*)(w + (49u << 20));               // 128 KiB
    float*          vssum= (float*)(w + (49u << 20) + (1u << 18));  // 128 KiB

    cast_f32_bf16<<<2048, 256, 0, stream>>>(X,  Xb, 524288);
    cast_f32_bf16<<<1024, 256, 0, stream>>>(Wq, Wb,                262144);
    cast_f32_bf16<<<1024, 256, 0, stream>>>(Wk, Wb + (1u << 20),   262144);
    cast_f32_bf16<<<1024, 256, 0, stream>>>(Wv, Wb + (2u << 20),   262144);
    cast_f32_bf16<<<1024, 256, 0, stream>>>(Wo, Wob,               262144);

    gemm_bf16<0><<<dim3(24, 16), 256, 0, stream>>>(Xb, Wb, Qf, nullptr, 2048, 3072, 1024);
    norms1<<<256, 256, 0, stream>>>(Qf, partial);
    norms2<<<1, 64, 0, stream>>>(partial, norms);
    chunk_sums<<<512, 256, 0, stream>>>(Kf, Vf, Ssum, zsum, vssum);
    chunk_scan<<<264, 256, 0, stream>>>(Ssum, zsum, vssum);
    intra_attn<<<512, 256, 0, stream>>>(Qf, Kf, Vf, Ssum, zsum, vssum, norms, vhb);
    gemm_bf16<1><<<dim3(8, 16), 256, 0, stream>>>(vhb, Wob, out, bo, 2048, 1024, 1024);
}

// Round 3
// 79.191 us; speedup vs baseline: 4.7752x; 1.6620x over previous
//
#include <hip/hip_runtime.h>

#define N_SEQ 2048
#define NH 16
#define DH 64
#define CHUNK 64
#define NCHUNK 32

typedef float f32x4 __attribute__((ext_vector_type(4)));
typedef __bf16 bf16x8 __attribute__((ext_vector_type(8)));
typedef unsigned short u16x4 __attribute__((ext_vector_type(4)));
typedef unsigned short u16x8 __attribute__((ext_vector_type(8)));

static __device__ inline unsigned short f2b(float x) {
    unsigned int u = __builtin_bit_cast(unsigned int, x);
    unsigned int r = (u + 0x7fffu + ((u >> 16) & 1u)) >> 16;  // RNE
    return (unsigned short)r;
}
static __device__ inline float b2f(unsigned short b) {
    return __builtin_bit_cast(float, (unsigned int)b << 16);
}
// swizzled elem offset in a [64 rows][64 bf16] LDS tile (row stride 128B):
// XOR 16B-block index with row&7 -> conflict-free b128 reads/writes
static __device__ inline int sw(int row, int col) {
    return row * 64 + (col ^ ((row & 7) << 3));
}

// ---------------------------------------------------------------- fused casts (X + 4 weights)
__global__ __launch_bounds__(256) void cast_all(
    const float* __restrict__ X, const float* __restrict__ Wq, const float* __restrict__ Wk,
    const float* __restrict__ Wv, const float* __restrict__ Wo,
    unsigned short* __restrict__ Xb, unsigned short* __restrict__ Wb,
    unsigned short* __restrict__ Wob) {
    int i = blockIdx.x * 256 + threadIdx.x;     // float4 id, total 1572864
    const float* src; unsigned short* dst; int off;
    if (i < 524288)       { src = X;  dst = Xb;               off = i; }
    else if (i < 786432)  { src = Wq; dst = Wb;               off = i - 524288; }
    else if (i < 1048576) { src = Wk; dst = Wb + (1u << 20);  off = i - 786432; }
    else if (i < 1310720) { src = Wv; dst = Wb + (2u << 20);  off = i - 1048576; }
    else                  { src = Wo; dst = Wob;              off = i - 1310720; }
    float4 v = reinterpret_cast<const float4*>(src)[off];
    u16x4 o;
    o[0] = f2b(v.x); o[1] = f2b(v.y); o[2] = f2b(v.z); o[3] = f2b(v.w);
    reinterpret_cast<u16x4*>(dst)[off] = o;
}

// ---------------------------------------------------------------- GEMM (bf16 MFMA, 128x128 tile, global_load_lds staging)
// MODE 0: write bf16 QKV [which][h][n][d];  MODE 1: f32 out[row*N+col] = acc + bias[col]
static __device__ inline void gload_lds16(const unsigned short* g, unsigned short* l) {
    __builtin_amdgcn_global_load_lds(
        (const __attribute__((address_space(1))) unsigned int*)g,
        (__attribute__((address_space(3))) unsigned int*)l, 16, 0, 0);
}

template<int MODE>
__global__ __launch_bounds__(256, 2) void gemm_bf16(
    const unsigned short* __restrict__ A,
    const unsigned short* __restrict__ B,
    float* __restrict__ outf,
    unsigned short* __restrict__ outb,
    const float* __restrict__ bias,
    int M, int N, int K)
{
    __shared__ __align__(16) unsigned short As[128][32];
    __shared__ __align__(16) unsigned short Bs[128][32];

    const int t = threadIdx.x;
    const int bn = blockIdx.x, bm = blockIdx.y;
    const int wave = t >> 6, lane = t & 63;
    const int wm = wave >> 1, wn = wave & 1;
    const int r16 = lane & 15, ks = lane >> 4;

    f32x4 acc[4][4] = {};

    const unsigned short* gA = A + (size_t)bm * 128 * K;
    const unsigned short* gB = B + (size_t)bn * 128 * K;
    const int lrow = lane >> 2;
    const int lcol = (lane & 3) * 8;

    for (int k0 = 0; k0 < K; k0 += 32) {
        __syncthreads();
        #pragma unroll
        for (int p = 0; p < 2; ++p) {
            int row = p * 64 + wave * 16;
            gload_lds16(&gA[(size_t)(row + lrow) * K + k0 + lcol], &As[row][0]);
            gload_lds16(&gB[(size_t)(row + lrow) * K + k0 + lcol], &Bs[row][0]);
        }
        __syncthreads();

        bf16x8 af[4], bfr[4];
        #pragma unroll
        for (int m = 0; m < 4; ++m)
            af[m] = *reinterpret_cast<const bf16x8*>(&As[wm * 64 + m * 16 + r16][ks * 8]);
        #pragma unroll
        for (int n = 0; n < 4; ++n)
            bfr[n] = *reinterpret_cast<const bf16x8*>(&Bs[wn * 64 + n * 16 + r16][ks * 8]);
        #pragma unroll
        for (int m = 0; m < 4; ++m)
            #pragma unroll
            for (int n = 0; n < 4; ++n)
                acc[m][n] = __builtin_amdgcn_mfma_f32_16x16x32_bf16(af[m], bfr[n], acc[m][n], 0, 0, 0);
    }

    #pragma unroll
    for (int m = 0; m < 4; ++m) {
        int row0 = bm * 128 + wm * 64 + m * 16 + ks * 4;
        #pragma unroll
        for (int n = 0; n < 4; ++n) {
            int col = bn * 128 + wn * 64 + n * 16 + r16;
            if (MODE == 0) {
                int wch = col >> 10, h = (col >> 6) & 15, d = col & 63;
                unsigned short* dst = outb + (size_t)wch * (NH * (size_t)N_SEQ * DH)
                                          + (size_t)h * N_SEQ * DH + d;
                #pragma unroll
                for (int j = 0; j < 4; ++j)
                    dst[(size_t)(row0 + j) * DH] = f2b(acc[m][n][j]);
            } else {
                float bv = bias[col];
                #pragma unroll
                for (int j = 0; j < 4; ++j)
                    outf[(size_t)(row0 + j) * N + col] = acc[m][n][j] + bv;
            }
        }
    }
}

// ---------------------------------------------------------------- per-head max L2 norm (bf16 input)
__global__ __launch_bounds__(256) void norms1(const unsigned short* __restrict__ QK,
                                              float* __restrict__ partial) {
    const int b = blockIdx.x;
    const int rc = b & 7, h = (b >> 3) & 15, which = b >> 7;
    const int t = threadIdx.x;
    const unsigned short* base = QK + ((size_t)(which * 16 + h) * N_SEQ + rc * 256 + t) * DH;
    float s = 0.f;
    #pragma unroll
    for (int i = 0; i < 8; ++i) {
        u16x8 v = *reinterpret_cast<const u16x8*>(base + i * 8);
        #pragma unroll
        for (int j = 0; j < 8; ++j) { float f = b2f(v[j]); s += f * f; }
    }
    #pragma unroll
    for (int off = 1; off < 64; off <<= 1) s = fmaxf(s, __shfl_xor(s, off));
    __shared__ float red[4];
    if ((t & 63) == 0) red[t >> 6] = s;
    __syncthreads();
    if (t == 0) partial[b] = fmaxf(fmaxf(red[0], red[1]), fmaxf(red[2], red[3]));
}

__global__ __launch_bounds__(64) void norms2(const float* __restrict__ partial,
                                             float* __restrict__ norms) {
    int t = threadIdx.x;
    if (t < 32) {
        float m = 0.f;
        #pragma unroll
        for (int j = 0; j < 8; ++j) m = fmaxf(m, partial[t * 8 + j]);
        norms[t] = sqrtf(m);
    }
}

// ---------------------------------------------------------------- per-chunk sums via MFMA: S = K^T V, z = sum k, vs = sum v
__global__ __launch_bounds__(256) void chunk_sums(const unsigned short* __restrict__ Kb,
                                                  const unsigned short* __restrict__ Vb,
                                                  float* __restrict__ Ssum,
                                                  float* __restrict__ zsum,
                                                  float* __restrict__ vssum) {
    const int h = blockIdx.x >> 5, c = blockIdx.x & 31;
    __shared__ __align__(16) unsigned short Kt[4096];   // [d][j] swizzled (= K^T)
    __shared__ __align__(16) unsigned short Vt[4096];   // [e][j] swizzled (= V^T)
    const size_t off = ((size_t)h * N_SEQ + c * CHUNK) * DH;
    const int t = threadIdx.x, lane = t & 63;

    {   // transposed gather: lane = column index -> coalesced global reads, 16B swizzled LDS writes
        const int d = t & 63, j0 = (t >> 6) * 16;
        unsigned short rk[16], rv[16];
        #pragma unroll
        for (int i = 0; i < 16; ++i) {
            rk[i] = Kb[off + (size_t)(j0 + i) * DH + d];
            rv[i] = Vb[off + (size_t)(j0 + i) * DH + d];
        }
        u16x8 a, b;
        #pragma unroll
        for (int i = 0; i < 8; ++i) { a[i] = rk[i]; b[i] = rk[8 + i]; }
        *reinterpret_cast<u16x8*>(&Kt[sw(d, j0)]) = a;
        *reinterpret_cast<u16x8*>(&Kt[sw(d, j0 + 8)]) = b;
        #pragma unroll
        for (int i = 0; i < 8; ++i) { a[i] = rv[i]; b[i] = rv[8 + i]; }
        *reinterpret_cast<u16x8*>(&Vt[sw(d, j0)]) = a;
        *reinterpret_cast<u16x8*>(&Vt[sw(d, j0 + 8)]) = b;
    }
    __syncthreads();

    const int w = t >> 6, cl = lane & 15, g = lane >> 4;
    bf16x8 ak0 = *reinterpret_cast<const bf16x8*>(&Kt[sw(w * 16 + cl, g * 8)]);
    bf16x8 ak1 = *reinterpret_cast<const bf16x8*>(&Kt[sw(w * 16 + cl, 32 + g * 8)]);
    f32x4 acc[4] = {};
    #pragma unroll
    for (int et = 0; et < 4; ++et) {
        bf16x8 b0 = *reinterpret_cast<const bf16x8*>(&Vt[sw(et * 16 + cl, g * 8)]);
        bf16x8 b1 = *reinterpret_cast<const bf16x8*>(&Vt[sw(et * 16 + cl, 32 + g * 8)]);
        acc[et] = __builtin_amdgcn_mfma_f32_16x16x32_bf16(ak0, b0, acc[et], 0, 0, 0);
        acc[et] = __builtin_amdgcn_mfma_f32_16x16x32_bf16(ak1, b1, acc[et], 0, 0, 0);
    }
    float* So = Ssum + (size_t)blockIdx.x * (DH * DH);
    #pragma unroll
    for (int et = 0; et < 4; ++et)
        #pragma unroll
        for (int j = 0; j < 4; ++j)
            So[(size_t)(w * 16 + g * 4 + j) * DH + et * 16 + cl] = acc[et][j];

    if (t < 64) {
        float z = 0.f;
        #pragma unroll
        for (int i = 0; i < 8; ++i) {
            u16x8 v = *reinterpret_cast<const u16x8*>(&Kt[sw(t, i * 8)]);
            #pragma unroll
            for (int k = 0; k < 8; ++k) z += b2f(v[k]);
        }
        zsum[(size_t)blockIdx.x * DH + t] = z;
    } else if (t < 128) {
        int e = t - 64;
        float z = 0.f;
        #pragma unroll
        for (int i = 0; i < 8; ++i) {
            u16x8 v = *reinterpret_cast<const u16x8*>(&Vt[sw(e, i * 8)]);
            #pragma unroll
            for (int k = 0; k < 8; ++k) z += b2f(v[k]);
        }
        vssum[(size_t)blockIdx.x * DH + e] = z;
    }
}

// ---------------------------------------------------------------- exclusive scan over chunks (parallel over elements)
__global__ __launch_bounds__(256) void chunk_scan(float* __restrict__ Ssum,
                                                  float* __restrict__ zsum,
                                                  float* __restrict__ vssum) {
    const int b = blockIdx.x;
    if (b < 256) {
        const int h = b >> 4;
        const int e = (b & 15) * 256 + threadIdx.x;
        size_t base = (size_t)h * NCHUNK * (DH * DH) + e;
        float run = 0.f;
        for (int c = 0; c < NCHUNK; ++c) {
            size_t idx = base + (size_t)c * (DH * DH);
            float tmp = Ssum[idx]; Ssum[idx] = run; run += tmp;
        }
    } else {
        const int g = (b - 256) * 256 + threadIdx.x;
        const int which = g >> 10, h = (g >> 6) & 15, e = g & 63;
        float* arr = which ? vssum : zsum;
        size_t base = (size_t)h * NCHUNK * DH + e;
        float run = 0.f;
        for (int c = 0; c < NCHUNK; ++c) {
            size_t idx = base + (size_t)c * DH;
            float tmp = arr[idx]; arr[idx] = run; run += tmp;
        }
    }
}

// ---------------------------------------------------------------- intra-chunk attention + combine, MFMA
__global__ __launch_bounds__(256) void intra_attn(
    const unsigned short* __restrict__ Qb, const unsigned short* __restrict__ Kb,
    const unsigned short* __restrict__ Vb,
    const float* __restrict__ Ssum, const float* __restrict__ zsum,
    const float* __restrict__ vssum, const float* __restrict__ norms,
    unsigned short* __restrict__ vhb) {
    const int h = blockIdx.x >> 5, c = blockIdx.x & 31;
    __shared__ __align__(16) unsigned short Ql[4096];   // [q][d] swizzled
    __shared__ __align__(16) unsigned short Kl[4096];   // [key][d] swizzled
    __shared__ __align__(16) unsigned short Vt[4096];   // [e][key] swizzled
    __shared__ __align__(16) unsigned short Sp[4096];   // [e][d] = bf16(alpha*S_prev[d][e]) swizzled
    __shared__ __align__(16) unsigned short Pl[4096];   // per-wave [16][64] swizzled
    __shared__ float zp[DH], vsp[DH];

    const int t = threadIdx.x, lane = t & 63, w = t >> 6;
    const float alpha = 1.f / (norms[h] * norms[16 + h]);
    const size_t off = ((size_t)h * N_SEQ + c * CHUNK) * DH;

    // Q, K: row-major coalesced loads, swizzled 16B writes
    #pragma unroll
    for (int p = 0; p < 2; ++p) {
        int lin = t + p * 256;           // u16x8 chunk 0..511
        int row = lin >> 3, col = (lin & 7) * 8;
        u16x8 q = *reinterpret_cast<const u16x8*>(Qb + off + (size_t)row * DH + col);
        u16x8 k = *reinterpret_cast<const u16x8*>(Kb + off + (size_t)row * DH + col);
        *reinterpret_cast<u16x8*>(&Ql[sw(row, col)]) = q;
        *reinterpret_cast<u16x8*>(&Kl[sw(row, col)]) = k;
    }
    // V transposed gather
    {
        const int e = t & 63, j0 = (t >> 6) * 16;
        unsigned short rv[16];
        #pragma unroll
        for (int i = 0; i < 16; ++i) rv[i] = Vb[off + (size_t)(j0 + i) * DH + e];
        u16x8 a, b;
        #pragma unroll
        for (int i = 0; i < 8; ++i) { a[i] = rv[i]; b[i] = rv[8 + i]; }
        *reinterpret_cast<u16x8*>(&Vt[sw(e, j0)]) = a;
        *reinterpret_cast<u16x8*>(&Vt[sw(e, j0 + 8)]) = b;
    }
    // S_prev transposed gather, alpha-prescaled, f32 -> bf16
    {
        const float* Sg = Ssum + (size_t)blockIdx.x * (DH * DH);
        const int e = t & 63, d0 = (t >> 6) * 16;
        u16x8 a, b;
        #pragma unroll
        for (int i = 0; i < 8; ++i) a[i] = f2b(alpha * Sg[(size_t)(d0 + i) * DH + e]);
        #pragma unroll
        for (int i = 0; i < 8; ++i) b[i] = f2b(alpha * Sg[(size_t)(d0 + 8 + i) * DH + e]);
        *reinterpret_cast<u16x8*>(&Sp[sw(e, d0)]) = a;
        *reinterpret_cast<u16x8*>(&Sp[sw(e, d0 + 8)]) = b;
    }
    if (t < 64) zp[t] = alpha * zsum[(size_t)blockIdx.x * DH + t];
    else if (t < 128) vsp[t - 64] = vssum[(size_t)blockIdx.x * DH + (t - 64)];
    __syncthreads();

    const int cl = lane & 15, g = lane >> 4;
    const int qrow = (w << 4) + cl;              // A-fragment row (q within chunk for this wave tile)

    bf16x8 aq0 = *reinterpret_cast<const bf16x8*>(&Ql[sw(qrow, g * 8)]);
    bf16x8 aq1 = *reinterpret_cast<const bf16x8*>(&Ql[sw(qrow, 32 + g * 8)]);

    // 1) acc = Q @ (alpha*S_prev)   [already alpha-scaled]
    f32x4 acc[4] = {};
    #pragma unroll
    for (int et = 0; et < 4; ++et) {
        bf16x8 b0 = *reinterpret_cast<const bf16x8*>(&Sp[sw(et * 16 + cl, g * 8)]);
        bf16x8 b1 = *reinterpret_cast<const bf16x8*>(&Sp[sw(et * 16 + cl, 32 + g * 8)]);
        acc[et] = __builtin_amdgcn_mfma_f32_16x16x32_bf16(aq0, b0, acc[et], 0, 0, 0);
        acc[et] = __builtin_amdgcn_mfma_f32_16x16x32_bf16(aq1, b1, acc[et], 0, 0, 0);
    }
    // 2) raw scores S = Q @ K^T
    f32x4 sacc[4] = {};
    #pragma unroll
    for (int kt = 0; kt < 4; ++kt) {
        bf16x8 b0 = *reinterpret_cast<const bf16x8*>(&Kl[sw(kt * 16 + cl, g * 8)]);
        bf16x8 b1 = *reinterpret_cast<const bf16x8*>(&Kl[sw(kt * 16 + cl, 32 + g * 8)]);
        sacc[kt] = __builtin_amdgcn_mfma_f32_16x16x32_bf16(aq0, b0, sacc[kt], 0, 0, 0);
        sacc[kt] = __builtin_amdgcn_mfma_f32_16x16x32_bf16(aq1, b1, sacc[kt], 0, 0, 0);
    }
    // 3) mask + 1 + alpha, den partials, stage P (per-wave LDS, swizzled)
    unsigned short* Pw = &Pl[w * 1024];
    float part[4] = {0.f, 0.f, 0.f, 0.f};
    #pragma unroll
    for (int kt = 0; kt < 4; ++kt) {
        int key = kt * 16 + cl;
        #pragma unroll
        for (int j = 0; j < 4; ++j) {
            int rr = g * 4 + j;
            int q = (w << 4) + rr;
            float s = (key <= q) ? fmaf(alpha, sacc[kt][j], 1.f) : 0.f;
            part[j] += s;
            Pw[rr * 64 + (key ^ ((rr & 7) << 3))] = f2b(s);
        }
    }
    // + alpha * q . z_prev  (zp prescaled)
    #pragma unroll
    for (int j = 0; j < 4; ++j) {
        int q = (w << 4) + g * 4 + j;
        float qz = 0.f;
        #pragma unroll
        for (int m = 0; m < 4; ++m) {
            int d = cl + m * 16;
            qz = fmaf(b2f(Ql[sw(q, d)]), zp[d], qz);
        }
        part[j] += qz;
    }
    #pragma unroll
    for (int o = 1; o < 16; o <<= 1)
        #pragma unroll
        for (int j = 0; j < 4; ++j) part[j] += __shfl_xor(part[j], o);
    float invden[4];
    #pragma unroll
    for (int j = 0; j < 4; ++j) invden[j] = 1.f / ((float)(c * CHUNK) + part[j]);

    // 4) acc += P @ V
    #pragma unroll
    for (int ks = 0; ks < 2; ++ks) {
        bf16x8 ap = *reinterpret_cast<const bf16x8*>(&Pw[cl * 64 + ((ks * 32 + g * 8) ^ ((cl & 7) << 3))]);
        #pragma unroll
        for (int et = 0; et < 4; ++et) {
            bf16x8 bv = *reinterpret_cast<const bf16x8*>(&Vt[sw(et * 16 + cl, ks * 32 + g * 8)]);
            acc[et] = __builtin_amdgcn_mfma_f32_16x16x32_bf16(ap, bv, acc[et], 0, 0, 0);
        }
    }
    // 5) epilogue: out = (vs_prev + acc) / den
    #pragma unroll
    for (int et = 0; et < 4; ++et)
        #pragma unroll
        for (int j = 0; j < 4; ++j) {
            int q = (w << 4) + g * 4 + j;
            int e = et * 16 + cl;
            float o = (vsp[e] + acc[et][j]) * invden[j];
            vhb[(size_t)(c * CHUNK + q) * (NH * DH) + h * DH + e] = f2b(o);
        }
}

// ---------------------------------------------------------------- launch
extern "C" void kernel_launch(void* const* d_in, const int* in_sizes, int n_in,
                              void* d_out, int out_size, void* d_ws, size_t ws_size,
                              hipStream_t stream) {
    const float* X  = (const float*)d_in[0];
    const float* Wq = (const float*)d_in[1];
    const float* Wk = (const float*)d_in[2];
    const float* Wv = (const float*)d_in[3];
    const float* Wo = (const float*)d_in[4];
    const float* bo = (const float*)d_in[5];
    float* out = (float*)d_out;

    char* w = (char*)d_ws;
    unsigned short* Xb   = (unsigned short*)(w);                    // 4 MiB [2048][1024]
    unsigned short* Wb   = (unsigned short*)(w + (4u  << 20));      // 6 MiB [3072][1024]
    unsigned short* Wob  = (unsigned short*)(w + (10u << 20));      // 2 MiB [1024][1024]
    unsigned short* Qb   = (unsigned short*)(w + (12u << 20));      // 4 MiB [16][2048][64] bf16
    unsigned short* vhb  = (unsigned short*)(w + (24u << 20));      // 4 MiB [2048][1024] bf16
    float*          norms= (float*)(w + (28u << 20));               // 32 f32
    float*          partial = norms + 128;                          // 256 f32
    float*          Ssum = (float*)(w + (29u << 20));               // 8 MiB [512][64][64] f32
    float*          zsum = (float*)(w + (37u << 20));               // 128 KiB
    float*          vssum= (float*)(w + (37u << 20) + (1u << 17));  // 128 KiB
    unsigned short* Kb = Qb + 2097152;
    unsigned short* Vb = Qb + 2u * 2097152;

    cast_all<<<6144, 256, 0, stream>>>(X, Wq, Wk, Wv, Wo, Xb, Wb, Wob);
    gemm_bf16<0><<<dim3(24, 16), 256, 0, stream>>>(Xb, Wb, nullptr, Qb, nullptr, 2048, 3072, 1024);
    norms1<<<256, 256, 0, stream>>>(Qb, partial);
    norms2<<<1, 64, 0, stream>>>(partial, norms);
    chunk_sums<<<512, 256, 0, stream>>>(Kb, Vb, Ssum, zsum, vssum);
    chunk_scan<<<264, 256, 0, stream>>>(Ssum, zsum, vssum);
    intra_attn<<<512, 256, 0, stream>>>(Qb, Kb, Vb, Ssum, zsum, vssum, norms, vhb);
    gemm_bf16<1><<<dim3(8, 16), 256, 0, stream>>>(vhb, Wob, out, nullptr, bo, 2048, 1024, 1024);
}

// Round 4
// 72.081 us; speedup vs baseline: 5.2463x; 1.0986x over previous
//
#include <hip/hip_runtime.h>

#define N_SEQ 2048
#define NH 16
#define DH 64
#define CHUNK 64
#define NCHUNK 32

typedef float f32x4 __attribute__((ext_vector_type(4)));
typedef __bf16 bf16x8 __attribute__((ext_vector_type(8)));
typedef unsigned short u16x4 __attribute__((ext_vector_type(4)));
typedef unsigned short u16x8 __attribute__((ext_vector_type(8)));

static __device__ inline unsigned short f2b(float x) {
    unsigned int u = __builtin_bit_cast(unsigned int, x);
    unsigned int r = (u + 0x7fffu + ((u >> 16) & 1u)) >> 16;  // RNE
    return (unsigned short)r;
}
static __device__ inline float b2f(unsigned short b) {
    return __builtin_bit_cast(float, (unsigned int)b << 16);
}
// swizzled elem offset in a [64 rows][64 bf16] LDS tile (row stride 128B)
static __device__ inline int sw(int row, int col) {
    return row * 64 + (col ^ ((row & 7) << 3));
}

// ---------------------------------------------------------------- fused casts (X + 4 weights)
__global__ __launch_bounds__(256) void cast_all(
    const float* __restrict__ X, const float* __restrict__ Wq, const float* __restrict__ Wk,
    const float* __restrict__ Wv, const float* __restrict__ Wo,
    unsigned short* __restrict__ Xb, unsigned short* __restrict__ Wb,
    unsigned short* __restrict__ Wob) {
    int i = blockIdx.x * 256 + threadIdx.x;     // float4 id, total 1572864
    const float* src; unsigned short* dst; int off;
    if (i < 524288)       { src = X;  dst = Xb;               off = i; }
    else if (i < 786432)  { src = Wq; dst = Wb;               off = i - 524288; }
    else if (i < 1048576) { src = Wk; dst = Wb + (1u << 20);  off = i - 786432; }
    else if (i < 1310720) { src = Wv; dst = Wb + (2u << 20);  off = i - 1048576; }
    else                  { src = Wo; dst = Wob;              off = i - 1310720; }
    float4 v = reinterpret_cast<const float4*>(src)[off];
    u16x4 o;
    o[0] = f2b(v.x); o[1] = f2b(v.y); o[2] = f2b(v.z); o[3] = f2b(v.w);
    reinterpret_cast<u16x4*>(dst)[off] = o;
}

// ---------------------------------------------------------------- GEMM (bf16 MFMA, BMx128 tile, global_load_lds staging)
static __device__ inline void gload_lds16(const unsigned short* g, unsigned short* l) {
    __builtin_amdgcn_global_load_lds(
        (const __attribute__((address_space(1))) unsigned int*)g,
        (__attribute__((address_space(3))) unsigned int*)l, 16, 0, 0);
}

// MODE 0 (BM=128): write bf16 QKV [which][h][n][d];  MODE 1 (BM=64): f32 out = acc + bias
template<int MODE, int BM>
__global__ __launch_bounds__(256, 2) void gemm_bf16(
    const unsigned short* __restrict__ A,
    const unsigned short* __restrict__ B,
    float* __restrict__ outf,
    unsigned short* __restrict__ outb,
    const float* __restrict__ bias,
    int M, int N, int K)
{
    __shared__ __align__(16) unsigned short As[BM][32];
    __shared__ __align__(16) unsigned short Bs[128][32];

    // XCD-aware bijective swizzle (grid count % 8 == 0), bn-major chunks:
    // each XCD keeps its B-panels resident in its private L2.
    const int L = blockIdx.y * gridDim.x + blockIdx.x;
    const int cpx = (gridDim.x * gridDim.y) >> 3;
    const int tile = (L & 7) * cpx + (L >> 3);
    const int bn = tile / gridDim.y;
    const int bm = tile % gridDim.y;

    const int t = threadIdx.x;
    const int wave = t >> 6, lane = t & 63;
    const int wm = wave >> 1, wn = wave & 1;
    const int r16 = lane & 15, ks = lane >> 4;
    constexpr int MFRAG = BM / 32;

    f32x4 acc[MFRAG][4] = {};

    const unsigned short* gA = A + (size_t)bm * BM * K;
    const unsigned short* gB = B + (size_t)bn * 128 * K;
    const int lrow = lane >> 2;
    const int lcol = (lane & 3) * 8;

    for (int k0 = 0; k0 < K; k0 += 32) {
        __syncthreads();
        #pragma unroll
        for (int p = 0; p < BM / 64; ++p) {
            int row = p * 64 + wave * 16;
            gload_lds16(&gA[(size_t)(row + lrow) * K + k0 + lcol], &As[row][0]);
        }
        #pragma unroll
        for (int p = 0; p < 2; ++p) {
            int row = p * 64 + wave * 16;
            gload_lds16(&gB[(size_t)(row + lrow) * K + k0 + lcol], &Bs[row][0]);
        }
        __syncthreads();

        bf16x8 af[MFRAG], bfr[4];
        #pragma unroll
        for (int m = 0; m < MFRAG; ++m)
            af[m] = *reinterpret_cast<const bf16x8*>(&As[wm * (BM / 2) + m * 16 + r16][ks * 8]);
        #pragma unroll
        for (int n = 0; n < 4; ++n)
            bfr[n] = *reinterpret_cast<const bf16x8*>(&Bs[wn * 64 + n * 16 + r16][ks * 8]);
        #pragma unroll
        for (int m = 0; m < MFRAG; ++m)
            #pragma unroll
            for (int n = 0; n < 4; ++n)
                acc[m][n] = __builtin_amdgcn_mfma_f32_16x16x32_bf16(af[m], bfr[n], acc[m][n], 0, 0, 0);
    }

    #pragma unroll
    for (int m = 0; m < MFRAG; ++m) {
        int row0 = bm * BM + wm * (BM / 2) + m * 16 + ks * 4;
        #pragma unroll
        for (int n = 0; n < 4; ++n) {
            int col = bn * 128 + wn * 64 + n * 16 + r16;
            if (MODE == 0) {
                int wch = col >> 10, h = (col >> 6) & 15, d = col & 63;
                unsigned short* dst = outb + (size_t)wch * (NH * (size_t)N_SEQ * DH)
                                          + (size_t)h * N_SEQ * DH + d;
                #pragma unroll
                for (int j = 0; j < 4; ++j)
                    dst[(size_t)(row0 + j) * DH] = f2b(acc[m][n][j]);
            } else {
                float bv = bias[col];
                #pragma unroll
                for (int j = 0; j < 4; ++j)
                    outf[(size_t)(row0 + j) * N + col] = acc[m][n][j] + bv;
            }
        }
    }
}

// ---------------------------------------------------------------- per-head max L2 norm partials (bf16 input)
__global__ __launch_bounds__(256) void norms1(const unsigned short* __restrict__ QK,
                                              float* __restrict__ partial) {
    const int b = blockIdx.x;
    const int rc = b & 7, h = (b >> 3) & 15, which = b >> 7;
    const int t = threadIdx.x;
    const unsigned short* base = QK + ((size_t)(which * 16 + h) * N_SEQ + rc * 256 + t) * DH;
    float s = 0.f;
    #pragma unroll
    for (int i = 0; i < 8; ++i) {
        u16x8 v = *reinterpret_cast<const u16x8*>(base + i * 8);
        #pragma unroll
        for (int j = 0; j < 8; ++j) { float f = b2f(v[j]); s += f * f; }
    }
    #pragma unroll
    for (int off = 1; off < 64; off <<= 1) s = fmaxf(s, __shfl_xor(s, off));
    __shared__ float red[4];
    if ((t & 63) == 0) red[t >> 6] = s;
    __syncthreads();
    if (t == 0) partial[b] = fmaxf(fmaxf(red[0], red[1]), fmaxf(red[2], red[3]));
}

// ---------------------------------------------------------------- per-chunk sums via MFMA: S = K^T V (bf16 out), z, vs
__global__ __launch_bounds__(256) void chunk_sums(const unsigned short* __restrict__ Kb,
                                                  const unsigned short* __restrict__ Vb,
                                                  unsigned short* __restrict__ Ssum,
                                                  float* __restrict__ zsum,
                                                  float* __restrict__ vssum) {
    const int h = blockIdx.x >> 5, c = blockIdx.x & 31;
    __shared__ __align__(16) unsigned short Kt[4096];   // [d][j] swizzled (= K^T)
    __shared__ __align__(16) unsigned short Vt[4096];   // [e][j] swizzled (= V^T)
    const size_t off = ((size_t)h * N_SEQ + c * CHUNK) * DH;
    const int t = threadIdx.x, lane = t & 63;

    {   // transposed gather
        const int d = t & 63, j0 = (t >> 6) * 16;
        unsigned short rk[16], rv[16];
        #pragma unroll
        for (int i = 0; i < 16; ++i) {
            rk[i] = Kb[off + (size_t)(j0 + i) * DH + d];
            rv[i] = Vb[off + (size_t)(j0 + i) * DH + d];
        }
        u16x8 a, b;
        #pragma unroll
        for (int i = 0; i < 8; ++i) { a[i] = rk[i]; b[i] = rk[8 + i]; }
        *reinterpret_cast<u16x8*>(&Kt[sw(d, j0)]) = a;
        *reinterpret_cast<u16x8*>(&Kt[sw(d, j0 + 8)]) = b;
        #pragma unroll
        for (int i = 0; i < 8; ++i) { a[i] = rv[i]; b[i] = rv[8 + i]; }
        *reinterpret_cast<u16x8*>(&Vt[sw(d, j0)]) = a;
        *reinterpret_cast<u16x8*>(&Vt[sw(d, j0 + 8)]) = b;
    }
    __syncthreads();

    const int w = t >> 6, cl = lane & 15, g = lane >> 4;
    bf16x8 ak0 = *reinterpret_cast<const bf16x8*>(&Kt[sw(w * 16 + cl, g * 8)]);
    bf16x8 ak1 = *reinterpret_cast<const bf16x8*>(&Kt[sw(w * 16 + cl, 32 + g * 8)]);
    f32x4 acc[4] = {};
    #pragma unroll
    for (int et = 0; et < 4; ++et) {
        bf16x8 b0 = *reinterpret_cast<const bf16x8*>(&Vt[sw(et * 16 + cl, g * 8)]);
        bf16x8 b1 = *reinterpret_cast<const bf16x8*>(&Vt[sw(et * 16 + cl, 32 + g * 8)]);
        acc[et] = __builtin_amdgcn_mfma_f32_16x16x32_bf16(ak0, b0, acc[et], 0, 0, 0);
        acc[et] = __builtin_amdgcn_mfma_f32_16x16x32_bf16(ak1, b1, acc[et], 0, 0, 0);
    }
    unsigned short* So = Ssum + (size_t)blockIdx.x * (DH * DH);
    #pragma unroll
    for (int et = 0; et < 4; ++et)
        #pragma unroll
        for (int j = 0; j < 4; ++j)
            So[(size_t)(w * 16 + g * 4 + j) * DH + et * 16 + cl] = f2b(acc[et][j]);

    if (t < 64) {
        float z = 0.f;
        #pragma unroll
        for (int i = 0; i < 8; ++i) {
            u16x8 v = *reinterpret_cast<const u16x8*>(&Kt[sw(t, i * 8)]);
            #pragma unroll
            for (int k = 0; k < 8; ++k) z += b2f(v[k]);
        }
        zsum[(size_t)blockIdx.x * DH + t] = z;
    } else if (t < 128) {
        int e = t - 64;
        float z = 0.f;
        #pragma unroll
        for (int i = 0; i < 8; ++i) {
            u16x8 v = *reinterpret_cast<const u16x8*>(&Vt[sw(e, i * 8)]);
            #pragma unroll
            for (int k = 0; k < 8; ++k) z += b2f(v[k]);
        }
        vssum[(size_t)blockIdx.x * DH + e] = z;
    }
}

// ---------------------------------------------------------------- exclusive scan over chunks (f32 run, bf16 in-place)
__global__ __launch_bounds__(256) void chunk_scan(unsigned short* __restrict__ Ssum,
                                                  float* __restrict__ zsum,
                                                  float* __restrict__ vssum) {
    const int b = blockIdx.x;
    if (b < 256) {
        const int h = b >> 4;
        const int e = (b & 15) * 256 + threadIdx.x;
        size_t base = (size_t)h * NCHUNK * (DH * DH) + e;
        float run = 0.f;
        for (int c = 0; c < NCHUNK; ++c) {
            size_t idx = base + (size_t)c * (DH * DH);
            float tmp = b2f(Ssum[idx]); Ssum[idx] = f2b(run); run += tmp;
        }
    } else {
        const int g = (b - 256) * 256 + threadIdx.x;
        const int which = g >> 10, h = (g >> 6) & 15, e = g & 63;
        float* arr = which ? vssum : zsum;
        size_t base = (size_t)h * NCHUNK * DH + e;
        float run = 0.f;
        for (int c = 0; c < NCHUNK; ++c) {
            size_t idx = base + (size_t)c * DH;
            float tmp = arr[idx]; arr[idx] = run; run += tmp;
        }
    }
}

// ---------------------------------------------------------------- intra-chunk attention + combine, MFMA
__global__ __launch_bounds__(256) void intra_attn(
    const unsigned short* __restrict__ Qb, const unsigned short* __restrict__ Kb,
    const unsigned short* __restrict__ Vb,
    const unsigned short* __restrict__ Ssum, const float* __restrict__ zsum,
    const float* __restrict__ vssum, const float* __restrict__ partial,
    unsigned short* __restrict__ vhb) {
    const int h = blockIdx.x >> 5, c = blockIdx.x & 31;
    __shared__ __align__(16) unsigned short Ql[4096];   // [q][d] swizzled
    __shared__ __align__(16) unsigned short Kl[4096];   // [key][d] swizzled
    __shared__ __align__(16) unsigned short Vt[4096];   // [e][key] swizzled
    __shared__ __align__(16) unsigned short Sp[4096];   // [e][d] = bf16(alpha*S_prev[d][e]) swizzled
    __shared__ __align__(16) unsigned short Pl[4096];   // per-wave [16][64] swizzled
    __shared__ float zp[DH], vsp[DH];

    const int t = threadIdx.x, lane = t & 63, w = t >> 6;
    // alpha from norm partials (folded norms2): redundant per-thread, L1-broadcast
    float qm = 0.f, km = 0.f;
    #pragma unroll
    for (int j2 = 0; j2 < 8; ++j2) {
        qm = fmaxf(qm, partial[h * 8 + j2]);
        km = fmaxf(km, partial[128 + h * 8 + j2]);
    }
    const float alpha = 1.f / sqrtf(qm * km);
    const size_t off = ((size_t)h * N_SEQ + c * CHUNK) * DH;

    // Q, K: row-major coalesced loads, swizzled 16B writes
    #pragma unroll
    for (int p = 0; p < 2; ++p) {
        int lin = t + p * 256;
        int row = lin >> 3, col = (lin & 7) * 8;
        u16x8 q = *reinterpret_cast<const u16x8*>(Qb + off + (size_t)row * DH + col);
        u16x8 k = *reinterpret_cast<const u16x8*>(Kb + off + (size_t)row * DH + col);
        *reinterpret_cast<u16x8*>(&Ql[sw(row, col)]) = q;
        *reinterpret_cast<u16x8*>(&Kl[sw(row, col)]) = k;
    }
    // V transposed gather
    {
        const int e = t & 63, j0 = (t >> 6) * 16;
        unsigned short rv[16];
        #pragma unroll
        for (int i = 0; i < 16; ++i) rv[i] = Vb[off + (size_t)(j0 + i) * DH + e];
        u16x8 a, b;
        #pragma unroll
        for (int i = 0; i < 8; ++i) { a[i] = rv[i]; b[i] = rv[8 + i]; }
        *reinterpret_cast<u16x8*>(&Vt[sw(e, j0)]) = a;
        *reinterpret_cast<u16x8*>(&Vt[sw(e, j0 + 8)]) = b;
    }
    // S_prev transposed gather (bf16 in), alpha-prescaled
    {
        const unsigned short* Sg = Ssum + (size_t)blockIdx.x * (DH * DH);
        const int e = t & 63, d0 = (t >> 6) * 16;
        u16x8 a, b;
        #pragma unroll
        for (int i = 0; i < 8; ++i) a[i] = f2b(alpha * b2f(Sg[(size_t)(d0 + i) * DH + e]));
        #pragma unroll
        for (int i = 0; i < 8; ++i) b[i] = f2b(alpha * b2f(Sg[(size_t)(d0 + 8 + i) * DH + e]));
        *reinterpret_cast<u16x8*>(&Sp[sw(e, d0)]) = a;
        *reinterpret_cast<u16x8*>(&Sp[sw(e, d0 + 8)]) = b;
    }
    if (t < 64) zp[t] = alpha * zsum[(size_t)blockIdx.x * DH + t];
    else if (t < 128) vsp[t - 64] = vssum[(size_t)blockIdx.x * DH + (t - 64)];
    __syncthreads();

    const int cl = lane & 15, g = lane >> 4;
    const int qrow = (w << 4) + cl;

    bf16x8 aq0 = *reinterpret_cast<const bf16x8*>(&Ql[sw(qrow, g * 8)]);
    bf16x8 aq1 = *reinterpret_cast<const bf16x8*>(&Ql[sw(qrow, 32 + g * 8)]);

    // 1) acc = Q @ (alpha*S_prev)
    f32x4 acc[4] = {};
    #pragma unroll
    for (int et = 0; et < 4; ++et) {
        bf16x8 b0 = *reinterpret_cast<const bf16x8*>(&Sp[sw(et * 16 + cl, g * 8)]);
        bf16x8 b1 = *reinterpret_cast<const bf16x8*>(&Sp[sw(et * 16 + cl, 32 + g * 8)]);
        acc[et] = __builtin_amdgcn_mfma_f32_16x16x32_bf16(aq0, b0, acc[et], 0, 0, 0);
        acc[et] = __builtin_amdgcn_mfma_f32_16x16x32_bf16(aq1, b1, acc[et], 0, 0, 0);
    }
    // 2) raw scores S = Q @ K^T
    f32x4 sacc[4] = {};
    #pragma unroll
    for (int kt = 0; kt < 4; ++kt) {
        bf16x8 b0 = *reinterpret_cast<const bf16x8*>(&Kl[sw(kt * 16 + cl, g * 8)]);
        bf16x8 b1 = *reinterpret_cast<const bf16x8*>(&Kl[sw(kt * 16 + cl, 32 + g * 8)]);
        sacc[kt] = __builtin_amdgcn_mfma_f32_16x16x32_bf16(aq0, b0, sacc[kt], 0, 0, 0);
        sacc[kt] = __builtin_amdgcn_mfma_f32_16x16x32_bf16(aq1, b1, sacc[kt], 0, 0, 0);
    }
    // 3) mask + 1 + alpha, den partials, stage P
    unsigned short* Pw = &Pl[w * 1024];
    float part[4] = {0.f, 0.f, 0.f, 0.f};
    #pragma unroll
    for (int kt = 0; kt < 4; ++kt) {
        int key = kt * 16 + cl;
        #pragma unroll
        for (int j = 0; j < 4; ++j) {
            int rr = g * 4 + j;
            int q = (w << 4) + rr;
            float s = (key <= q) ? fmaf(alpha, sacc[kt][j], 1.f) : 0.f;
            part[j] += s;
            Pw[rr * 64 + (key ^ ((rr & 7) << 3))] = f2b(s);
        }
    }
    #pragma unroll
    for (int j = 0; j < 4; ++j) {
        int q = (w << 4) + g * 4 + j;
        float qz = 0.f;
        #pragma unroll
        for (int m = 0; m < 4; ++m) {
            int d = cl + m * 16;
            qz = fmaf(b2f(Ql[sw(q, d)]), zp[d], qz);
        }
        part[j] += qz;
    }
    #pragma unroll
    for (int o = 1; o < 16; o <<= 1)
        #pragma unroll
        for (int j = 0; j < 4; ++j) part[j] += __shfl_xor(part[j], o);
    float invden[4];
    #pragma unroll
    for (int j = 0; j < 4; ++j) invden[j] = 1.f / ((float)(c * CHUNK) + part[j]);

    // 4) acc += P @ V
    #pragma unroll
    for (int ks = 0; ks < 2; ++ks) {
        bf16x8 ap = *reinterpret_cast<const bf16x8*>(&Pw[cl * 64 + ((ks * 32 + g * 8) ^ ((cl & 7) << 3))]);
        #pragma unroll
        for (int et = 0; et < 4; ++et) {
            bf16x8 bv = *reinterpret_cast<const bf16x8*>(&Vt[sw(et * 16 + cl, ks * 32 + g * 8)]);
            acc[et] = __builtin_amdgcn_mfma_f32_16x16x32_bf16(ap, bv, acc[et], 0, 0, 0);
        }
    }
    // 5) epilogue
    #pragma unroll
    for (int et = 0; et < 4; ++et)
        #pragma unroll
        for (int j = 0; j < 4; ++j) {
            int q = (w << 4) + g * 4 + j;
            int e = et * 16 + cl;
            float o = (vsp[e] + acc[et][j]) * invden[j];
            vhb[(size_t)(c * CHUNK + q) * (NH * DH) + h * DH + e] = f2b(o);
        }
}

// ---------------------------------------------------------------- launch
extern "C" void kernel_launch(void* const* d_in, const int* in_sizes, int n_in,
                              void* d_out, int out_size, void* d_ws, size_t ws_size,
                              hipStream_t stream) {
    const float* X  = (const float*)d_in[0];
    const float* Wq = (const float*)d_in[1];
    const float* Wk = (const float*)d_in[2];
    const float* Wv = (const float*)d_in[3];
    const float* Wo = (const float*)d_in[4];
    const float* bo = (const float*)d_in[5];
    float* out = (float*)d_out;

    char* w = (char*)d_ws;
    unsigned short* Xb   = (unsigned short*)(w);                    // 4 MiB [2048][1024]
    unsigned short* Wb   = (unsigned short*)(w + (4u  << 20));      // 6 MiB [3072][1024]
    unsigned short* Wob  = (unsigned short*)(w + (10u << 20));      // 2 MiB [1024][1024]
    unsigned short* Qb   = (unsigned short*)(w + (12u << 20));      // 12 MiB [3][16][2048][64] bf16
    unsigned short* vhb  = (unsigned short*)(w + (24u << 20));      // 4 MiB [2048][1024] bf16
    float*          partial = (float*)(w + (28u << 20));            // 256 f32
    unsigned short* Ssum = (unsigned short*)(w + (29u << 20));      // 4 MiB [512][64][64] bf16
    float*          zsum = (float*)(w + (34u << 20));               // 128 KiB
    float*          vssum= (float*)(w + (34u << 20) + (1u << 17));  // 128 KiB
    unsigned short* Kb = Qb + 2097152;
    unsigned short* Vb = Qb + 2u * 2097152;

    cast_all<<<6144, 256, 0, stream>>>(X, Wq, Wk, Wv, Wo, Xb, Wb, Wob);
    gemm_bf16<0, 128><<<dim3(24, 16), 256, 0, stream>>>(Xb, Wb, nullptr, Qb, nullptr, 2048, 3072, 1024);
    norms1<<<256, 256, 0, stream>>>(Qb, partial);
    chunk_sums<<<512, 256, 0, stream>>>(Kb, Vb, Ssum, zsum, vssum);
    chunk_scan<<<264, 256, 0, stream>>>(Ssum, zsum, vssum);
    intra_attn<<<512, 256, 0, stream>>>(Qb, Kb, Vb, Ssum, zsum, vssum, partial, vhb);
    gemm_bf16<1, 64><<<dim3(8, 32), 256, 0, stream>>>(vhb, Wob, out, nullptr, bo, 2048, 1024, 1024);
}

// Round 5
// 68.505 us; speedup vs baseline: 5.5202x; 1.0522x over previous
//
#include <hip/hip_runtime.h>

#define N_SEQ 2048
#define NH 16
#define DH 64
#define CHUNK 64
#define NCHUNK 32

typedef float f32x4 __attribute__((ext_vector_type(4)));
typedef __bf16 bf16x8 __attribute__((ext_vector_type(8)));
typedef unsigned short u16x4 __attribute__((ext_vector_type(4)));
typedef unsigned short u16x8 __attribute__((ext_vector_type(8)));

static __device__ inline unsigned short f2b(float x) {
    unsigned int u = __builtin_bit_cast(unsigned int, x);
    unsigned int r = (u + 0x7fffu + ((u >> 16) & 1u)) >> 16;  // RNE
    return (unsigned short)r;
}
static __device__ inline float b2f(unsigned short b) {
    return __builtin_bit_cast(float, (unsigned int)b << 16);
}
// swizzled elem offset in a [64 rows][64 bf16] LDS tile (row stride 128B)
static __device__ inline int sw(int row, int col) {
    return row * 64 + (col ^ ((row & 7) << 3));
}

// ---------------------------------------------------------------- fused casts (X + 4 weights) + zero norm buffer
__global__ __launch_bounds__(256) void cast_all(
    const float* __restrict__ X, const float* __restrict__ Wq, const float* __restrict__ Wk,
    const float* __restrict__ Wv, const float* __restrict__ Wo,
    unsigned short* __restrict__ Xb, unsigned short* __restrict__ Wb,
    unsigned short* __restrict__ Wob, float* __restrict__ nrm) {
    if (blockIdx.x == 0 && threadIdx.x < 32) nrm[threadIdx.x] = 0.f;
    int i = blockIdx.x * 256 + threadIdx.x;     // float4 id, total 1572864
    const float* src; unsigned short* dst; int off;
    if (i < 524288)       { src = X;  dst = Xb;               off = i; }
    else if (i < 786432)  { src = Wq; dst = Wb;               off = i - 524288; }
    else if (i < 1048576) { src = Wk; dst = Wb + (1u << 20);  off = i - 786432; }
    else if (i < 1310720) { src = Wv; dst = Wb + (2u << 20);  off = i - 1048576; }
    else                  { src = Wo; dst = Wob;              off = i - 1310720; }
    float4 v = reinterpret_cast<const float4*>(src)[off];
    u16x4 o;
    o[0] = f2b(v.x); o[1] = f2b(v.y); o[2] = f2b(v.z); o[3] = f2b(v.w);
    reinterpret_cast<u16x4*>(dst)[off] = o;
}

// ---------------------------------------------------------------- GEMM (bf16 MFMA, BMx128 tile, BK=64, swizzled LDS)
static __device__ inline void gload_lds16(const unsigned short* g, unsigned short* l) {
    __builtin_amdgcn_global_load_lds(
        (const __attribute__((address_space(1))) unsigned int*)g,
        (__attribute__((address_space(3))) unsigned int*)l, 16, 0, 0);
}

// MODE 0 (BM=128): write bf16 QKV [which][h][n][d] + per-head max-sumsq atomics
// MODE 1 (BM=64):  f32 out = acc + bias
template<int MODE, int BM>
__global__ __launch_bounds__(256, 2) void gemm_bf16(
    const unsigned short* __restrict__ A,
    const unsigned short* __restrict__ B,
    float* __restrict__ outf,
    unsigned short* __restrict__ outb,
    const float* __restrict__ bias,
    float* __restrict__ nrm,
    int M, int N, int K)
{
    // LDS: row stride 128B; logical 16B-slot s stored at physical p = s ^ (row&7).
    // gload_lds writes linearly (p = lane&7), so the SOURCE is pre-swizzled; reads
    // apply the same XOR -> each 16-lane read phase spans all 8 granule classes (conflict-free).
    __shared__ __align__(16) unsigned short As[BM][64];
    __shared__ __align__(16) unsigned short Bs[128][64];

    // XCD-aware bijective swizzle (grid count % 8 == 0), bn-major chunks
    const int L = blockIdx.y * gridDim.x + blockIdx.x;
    const int cpx = (gridDim.x * gridDim.y) >> 3;
    const int tile = (L & 7) * cpx + (L >> 3);
    const int bn = tile / gridDim.y;
    const int bm = tile % gridDim.y;

    const int t = threadIdx.x;
    const int wave = t >> 6, lane = t & 63;
    const int wm = wave >> 1, wn = wave & 1;
    const int r16 = lane & 15, ks = lane >> 4;
    constexpr int MFRAG = BM / 32;

    f32x4 acc[MFRAG][4] = {};

    const unsigned short* gA = A + (size_t)bm * BM * K;
    const unsigned short* gB = B + (size_t)bn * 128 * K;
    const int lrow = lane >> 3;                              // 0..7
    const int scol = (((lane & 7) ^ (lrow & 7)) << 3);       // pre-swizzled source col (elems)
    const int rsw = (r16 & 7) << 3;                          // read-side XOR (elems)

    for (int k0 = 0; k0 < K; k0 += 64) {
        __syncthreads();
        #pragma unroll
        for (int g = 0; g < BM / 32; ++g) {
            int r0 = wave * (BM / 4) + g * 8;
            gload_lds16(&gA[(size_t)(r0 + lrow) * K + k0 + scol], &As[r0][0]);
        }
        #pragma unroll
        for (int g = 0; g < 4; ++g) {
            int r0 = wave * 32 + g * 8;
            gload_lds16(&gB[(size_t)(r0 + lrow) * K + k0 + scol], &Bs[r0][0]);
        }
        __syncthreads();

        #pragma unroll
        for (int ksub = 0; ksub < 2; ++ksub) {
            const int sl = (((ksub << 2) + ks) << 3) ^ rsw;  // swizzled slot byte/2 offset
            bf16x8 af[MFRAG], bfr[4];
            #pragma unroll
            for (int m = 0; m < MFRAG; ++m)
                af[m] = *reinterpret_cast<const bf16x8*>(&As[wm * (BM / 2) + m * 16 + r16][sl]);
            #pragma unroll
            for (int n = 0; n < 4; ++n)
                bfr[n] = *reinterpret_cast<const bf16x8*>(&Bs[wn * 64 + n * 16 + r16][sl]);
            #pragma unroll
            for (int m = 0; m < MFRAG; ++m)
                #pragma unroll
                for (int n = 0; n < 4; ++n)
                    acc[m][n] = __builtin_amdgcn_mfma_f32_16x16x32_bf16(af[m], bfr[n], acc[m][n], 0, 0, 0);
        }
    }

    #pragma unroll
    for (int m = 0; m < MFRAG; ++m) {
        int row0 = bm * BM + wm * (BM / 2) + m * 16 + ks * 4;
        #pragma unroll
        for (int n = 0; n < 4; ++n) {
            int col = bn * 128 + wn * 64 + n * 16 + r16;
            if (MODE == 0) {
                int wch = col >> 10, h = (col >> 6) & 15, d = col & 63;
                unsigned short* dst = outb + (size_t)wch * (NH * (size_t)N_SEQ * DH)
                                          + (size_t)h * N_SEQ * DH + d;
                #pragma unroll
                for (int j = 0; j < 4; ++j)
                    dst[(size_t)(row0 + j) * DH] = f2b(acc[m][n][j]);
            } else {
                float bv = bias[col];
                #pragma unroll
                for (int j = 0; j < 4; ++j)
                    outf[(size_t)(row0 + j) * N + col] = acc[m][n][j] + bv;
            }
        }
    }

    // fused per-head max row-sumsq (q,k only) from f32 accumulators
    if (MODE == 0) {
        const int colbase = bn * 128 + wn * 64;   // one (which, head) group per wave
        const int wch = colbase >> 10;
        if (wch < 2) {
            const int h = (colbase >> 6) & 15;
            float mx = 0.f;
            #pragma unroll
            for (int m = 0; m < MFRAG; ++m)
                #pragma unroll
                for (int j = 0; j < 4; ++j) {
                    float rs = 0.f;
                    #pragma unroll
                    for (int n = 0; n < 4; ++n) rs = fmaf(acc[m][n][j], acc[m][n][j], rs);
                    rs += __shfl_xor(rs, 1);
                    rs += __shfl_xor(rs, 2);
                    rs += __shfl_xor(rs, 4);
                    rs += __shfl_xor(rs, 8);
                    mx = fmaxf(mx, rs);
                }
            mx = fmaxf(mx, __shfl_xor(mx, 16));
            mx = fmaxf(mx, __shfl_xor(mx, 32));
            if (lane == 0)
                atomicMax(reinterpret_cast<unsigned int*>(&nrm[wch * 16 + h]),
                          __builtin_bit_cast(unsigned int, mx));
        }
    }
}

// ---------------------------------------------------------------- per-chunk sums via MFMA: S = K^T V (bf16 out), z, vs
__global__ __launch_bounds__(256) void chunk_sums(const unsigned short* __restrict__ Kb,
                                                  const unsigned short* __restrict__ Vb,
                                                  unsigned short* __restrict__ Ssum,
                                                  float* __restrict__ zsum,
                                                  float* __restrict__ vssum) {
    const int h = blockIdx.x >> 5, c = blockIdx.x & 31;
    __shared__ __align__(16) unsigned short Kt[4096];   // [d][j] swizzled (= K^T)
    __shared__ __align__(16) unsigned short Vt[4096];   // [e][j] swizzled (= V^T)
    const size_t off = ((size_t)h * N_SEQ + c * CHUNK) * DH;
    const int t = threadIdx.x, lane = t & 63;

    {   // transposed gather
        const int d = t & 63, j0 = (t >> 6) * 16;
        unsigned short rk[16], rv[16];
        #pragma unroll
        for (int i = 0; i < 16; ++i) {
            rk[i] = Kb[off + (size_t)(j0 + i) * DH + d];
            rv[i] = Vb[off + (size_t)(j0 + i) * DH + d];
        }
        u16x8 a, b;
        #pragma unroll
        for (int i = 0; i < 8; ++i) { a[i] = rk[i]; b[i] = rk[8 + i]; }
        *reinterpret_cast<u16x8*>(&Kt[sw(d, j0)]) = a;
        *reinterpret_cast<u16x8*>(&Kt[sw(d, j0 + 8)]) = b;
        #pragma unroll
        for (int i = 0; i < 8; ++i) { a[i] = rv[i]; b[i] = rv[8 + i]; }
        *reinterpret_cast<u16x8*>(&Vt[sw(d, j0)]) = a;
        *reinterpret_cast<u16x8*>(&Vt[sw(d, j0 + 8)]) = b;
    }
    __syncthreads();

    const int w = t >> 6, cl = lane & 15, g = lane >> 4;
    bf16x8 ak0 = *reinterpret_cast<const bf16x8*>(&Kt[sw(w * 16 + cl, g * 8)]);
    bf16x8 ak1 = *reinterpret_cast<const bf16x8*>(&Kt[sw(w * 16 + cl, 32 + g * 8)]);
    f32x4 acc[4] = {};
    #pragma unroll
    for (int et = 0; et < 4; ++et) {
        bf16x8 b0 = *reinterpret_cast<const bf16x8*>(&Vt[sw(et * 16 + cl, g * 8)]);
        bf16x8 b1 = *reinterpret_cast<const bf16x8*>(&Vt[sw(et * 16 + cl, 32 + g * 8)]);
        acc[et] = __builtin_amdgcn_mfma_f32_16x16x32_bf16(ak0, b0, acc[et], 0, 0, 0);
        acc[et] = __builtin_amdgcn_mfma_f32_16x16x32_bf16(ak1, b1, acc[et], 0, 0, 0);
    }
    unsigned short* So = Ssum + (size_t)blockIdx.x * (DH * DH);
    #pragma unroll
    for (int et = 0; et < 4; ++et)
        #pragma unroll
        for (int j = 0; j < 4; ++j)
            So[(size_t)(w * 16 + g * 4 + j) * DH + et * 16 + cl] = f2b(acc[et][j]);

    if (t < 64) {
        float z = 0.f;
        #pragma unroll
        for (int i = 0; i < 8; ++i) {
            u16x8 v = *reinterpret_cast<const u16x8*>(&Kt[sw(t, i * 8)]);
            #pragma unroll
            for (int k = 0; k < 8; ++k) z += b2f(v[k]);
        }
        zsum[(size_t)blockIdx.x * DH + t] = z;
    } else if (t < 128) {
        int e = t - 64;
        float z = 0.f;
        #pragma unroll
        for (int i = 0; i < 8; ++i) {
            u16x8 v = *reinterpret_cast<const u16x8*>(&Vt[sw(e, i * 8)]);
            #pragma unroll
            for (int k = 0; k < 8; ++k) z += b2f(v[k]);
        }
        vssum[(size_t)blockIdx.x * DH + e] = z;
    }
}

// ---------------------------------------------------------------- exclusive scan over chunks (f32 run, bf16 in-place)
__global__ __launch_bounds__(256) void chunk_scan(unsigned short* __restrict__ Ssum,
                                                  float* __restrict__ zsum,
                                                  float* __restrict__ vssum) {
    const int b = blockIdx.x;
    if (b < 256) {
        const int h = b >> 4;
        const int e = (b & 15) * 256 + threadIdx.x;
        size_t base = (size_t)h * NCHUNK * (DH * DH) + e;
        float run = 0.f;
        for (int c = 0; c < NCHUNK; ++c) {
            size_t idx = base + (size_t)c * (DH * DH);
            float tmp = b2f(Ssum[idx]); Ssum[idx] = f2b(run); run += tmp;
        }
    } else {
        const int g = (b - 256) * 256 + threadIdx.x;
        const int which = g >> 10, h = (g >> 6) & 15, e = g & 63;
        float* arr = which ? vssum : zsum;
        size_t base = (size_t)h * NCHUNK * DH + e;
        float run = 0.f;
        for (int c = 0; c < NCHUNK; ++c) {
            size_t idx = base + (size_t)c * DH;
            float tmp = arr[idx]; arr[idx] = run; run += tmp;
        }
    }
}

// ---------------------------------------------------------------- intra-chunk attention + combine, MFMA
__global__ __launch_bounds__(256) void intra_attn(
    const unsigned short* __restrict__ Qb, const unsigned short* __restrict__ Kb,
    const unsigned short* __restrict__ Vb,
    const unsigned short* __restrict__ Ssum, const float* __restrict__ zsum,
    const float* __restrict__ vssum, const float* __restrict__ nrm,
    unsigned short* __restrict__ vhb) {
    const int h = blockIdx.x >> 5, c = blockIdx.x & 31;
    __shared__ __align__(16) unsigned short Ql[4096];   // [q][d] swizzled
    __shared__ __align__(16) unsigned short Kl[4096];   // [key][d] swizzled
    __shared__ __align__(16) unsigned short Vt[4096];   // [e][key] swizzled
    __shared__ __align__(16) unsigned short Sp[4096];   // [e][d] = bf16(alpha*S_prev[d][e]) swizzled
    __shared__ __align__(16) unsigned short Pl[4096];   // per-wave [16][64] swizzled
    __shared__ float zp[DH], vsp[DH];

    const int t = threadIdx.x, lane = t & 63, w = t >> 6;
    const float alpha = 1.f / sqrtf(nrm[h] * nrm[16 + h]);   // 1/(qn*kn), nrm = max sumsq
    const size_t off = ((size_t)h * N_SEQ + c * CHUNK) * DH;

    // Q, K: row-major coalesced loads, swizzled 16B writes
    #pragma unroll
    for (int p = 0; p < 2; ++p) {
        int lin = t + p * 256;
        int row = lin >> 3, col = (lin & 7) * 8;
        u16x8 q = *reinterpret_cast<const u16x8*>(Qb + off + (size_t)row * DH + col);
        u16x8 k = *reinterpret_cast<const u16x8*>(Kb + off + (size_t)row * DH + col);
        *reinterpret_cast<u16x8*>(&Ql[sw(row, col)]) = q;
        *reinterpret_cast<u16x8*>(&Kl[sw(row, col)]) = k;
    }
    // V transposed gather
    {
        const int e = t & 63, j0 = (t >> 6) * 16;
        unsigned short rv[16];
        #pragma unroll
        for (int i = 0; i < 16; ++i) rv[i] = Vb[off + (size_t)(j0 + i) * DH + e];
        u16x8 a, b;
        #pragma unroll
        for (int i = 0; i < 8; ++i) { a[i] = rv[i]; b[i] = rv[8 + i]; }
        *reinterpret_cast<u16x8*>(&Vt[sw(e, j0)]) = a;
        *reinterpret_cast<u16x8*>(&Vt[sw(e, j0 + 8)]) = b;
    }
    // S_prev transposed gather (bf16 in), alpha-prescaled
    {
        const unsigned short* Sg = Ssum + (size_t)blockIdx.x * (DH * DH);
        const int e = t & 63, d0 = (t >> 6) * 16;
        u16x8 a, b;
        #pragma unroll
        for (int i = 0; i < 8; ++i) a[i] = f2b(alpha * b2f(Sg[(size_t)(d0 + i) * DH + e]));
        #pragma unroll
        for (int i = 0; i < 8; ++i) b[i] = f2b(alpha * b2f(Sg[(size_t)(d0 + 8 + i) * DH + e]));
        *reinterpret_cast<u16x8*>(&Sp[sw(e, d0)]) = a;
        *reinterpret_cast<u16x8*>(&Sp[sw(e, d0 + 8)]) = b;
    }
    if (t < 64) zp[t] = alpha * zsum[(size_t)blockIdx.x * DH + t];
    else if (t < 128) vsp[t - 64] = vssum[(size_t)blockIdx.x * DH + (t - 64)];
    __syncthreads();

    const int cl = lane & 15, g = lane >> 4;
    const int qrow = (w << 4) + cl;

    bf16x8 aq0 = *reinterpret_cast<const bf16x8*>(&Ql[sw(qrow, g * 8)]);
    bf16x8 aq1 = *reinterpret_cast<const bf16x8*>(&Ql[sw(qrow, 32 + g * 8)]);

    // 1) acc = Q @ (alpha*S_prev)
    f32x4 acc[4] = {};
    #pragma unroll
    for (int et = 0; et < 4; ++et) {
        bf16x8 b0 = *reinterpret_cast<const bf16x8*>(&Sp[sw(et * 16 + cl, g * 8)]);
        bf16x8 b1 = *reinterpret_cast<const bf16x8*>(&Sp[sw(et * 16 + cl, 32 + g * 8)]);
        acc[et] = __builtin_amdgcn_mfma_f32_16x16x32_bf16(aq0, b0, acc[et], 0, 0, 0);
        acc[et] = __builtin_amdgcn_mfma_f32_16x16x32_bf16(aq1, b1, acc[et], 0, 0, 0);
    }
    // 2) raw scores S = Q @ K^T
    f32x4 sacc[4] = {};
    #pragma unroll
    for (int kt = 0; kt < 4; ++kt) {
        bf16x8 b0 = *reinterpret_cast<const bf16x8*>(&Kl[sw(kt * 16 + cl, g * 8)]);
        bf16x8 b1 = *reinterpret_cast<const bf16x8*>(&Kl[sw(kt * 16 + cl, 32 + g * 8)]);
        sacc[kt] = __builtin_amdgcn_mfma_f32_16x16x32_bf16(aq0, b0, sacc[kt], 0, 0, 0);
        sacc[kt] = __builtin_amdgcn_mfma_f32_16x16x32_bf16(aq1, b1, sacc[kt], 0, 0, 0);
    }
    // 3) mask + 1 + alpha, den partials, stage P
    unsigned short* Pw = &Pl[w * 1024];
    float part[4] = {0.f, 0.f, 0.f, 0.f};
    #pragma unroll
    for (int kt = 0; kt < 4; ++kt) {
        int key = kt * 16 + cl;
        #pragma unroll
        for (int j = 0; j < 4; ++j) {
            int rr = g * 4 + j;
            int q = (w << 4) + rr;
            float s = (key <= q) ? fmaf(alpha, sacc[kt][j], 1.f) : 0.f;
            part[j] += s;
            Pw[rr * 64 + (key ^ ((rr & 7) << 3))] = f2b(s);
        }
    }
    #pragma unroll
    for (int j = 0; j < 4; ++j) {
        int q = (w << 4) + g * 4 + j;
        float qz = 0.f;
        #pragma unroll
        for (int m = 0; m < 4; ++m) {
            int d = cl + m * 16;
            qz = fmaf(b2f(Ql[sw(q, d)]), zp[d], qz);
        }
        part[j] += qz;
    }
    #pragma unroll
    for (int o = 1; o < 16; o <<= 1)
        #pragma unroll
        for (int j = 0; j < 4; ++j) part[j] += __shfl_xor(part[j], o);
    float invden[4];
    #pragma unroll
    for (int j = 0; j < 4; ++j) invden[j] = 1.f / ((float)(c * CHUNK) + part[j]);

    // 4) acc += P @ V
    #pragma unroll
    for (int ks = 0; ks < 2; ++ks) {
        bf16x8 ap = *reinterpret_cast<const bf16x8*>(&Pw[cl * 64 + ((ks * 32 + g * 8) ^ ((cl & 7) << 3))]);
        #pragma unroll
        for (int et = 0; et < 4; ++et) {
            bf16x8 bv = *reinterpret_cast<const bf16x8*>(&Vt[sw(et * 16 + cl, ks * 32 + g * 8)]);
            acc[et] = __builtin_amdgcn_mfma_f32_16x16x32_bf16(ap, bv, acc[et], 0, 0, 0);
        }
    }
    // 5) epilogue
    #pragma unroll
    for (int et = 0; et < 4; ++et)
        #pragma unroll
        for (int j = 0; j < 4; ++j) {
            int q = (w << 4) + g * 4 + j;
            int e = et * 16 + cl;
            float o = (vsp[e] + acc[et][j]) * invden[j];
            vhb[(size_t)(c * CHUNK + q) * (NH * DH) + h * DH + e] = f2b(o);
        }
}

// ---------------------------------------------------------------- launch
extern "C" void kernel_launch(void* const* d_in, const int* in_sizes, int n_in,
                              void* d_out, int out_size, void* d_ws, size_t ws_size,
                              hipStream_t stream) {
    const float* X  = (const float*)d_in[0];
    const float* Wq = (const float*)d_in[1];
    const float* Wk = (const float*)d_in[2];
    const float* Wv = (const float*)d_in[3];
    const float* Wo = (const float*)d_in[4];
    const float* bo = (const float*)d_in[5];
    float* out = (float*)d_out;

    char* w = (char*)d_ws;
    unsigned short* Xb   = (unsigned short*)(w);                    // 4 MiB [2048][1024]
    unsigned short* Wb   = (unsigned short*)(w + (4u  << 20));      // 6 MiB [3072][1024]
    unsigned short* Wob  = (unsigned short*)(w + (10u << 20));      // 2 MiB [1024][1024]
    unsigned short* Qb   = (unsigned short*)(w + (12u << 20));      // 12 MiB [3][16][2048][64] bf16
    unsigned short* vhb  = (unsigned short*)(w + (24u << 20));      // 4 MiB [2048][1024] bf16
    float*          nrm  = (float*)(w + (28u << 20));               // 32 f32 (max sumsq per q/k head)
    unsigned short* Ssum = (unsigned short*)(w + (29u << 20));      // 4 MiB [512][64][64] bf16
    float*          zsum = (float*)(w + (34u << 20));               // 128 KiB
    float*          vssum= (float*)(w + (34u << 20) + (1u << 17));  // 128 KiB
    unsigned short* Kb = Qb + 2097152;
    unsigned short* Vb = Qb + 2u * 2097152;

    cast_all<<<6144, 256, 0, stream>>>(X, Wq, Wk, Wv, Wo, Xb, Wb, Wob, nrm);
    gemm_bf16<0, 128><<<dim3(24, 16), 256, 0, stream>>>(Xb, Wb, nullptr, Qb, nullptr, nrm, 2048, 3072, 1024);
    chunk_sums<<<512, 256, 0, stream>>>(Kb, Vb, Ssum, zsum, vssum);
    chunk_scan<<<264, 256, 0, stream>>>(Ssum, zsum, vssum);
    intra_attn<<<512, 256, 0, stream>>>(Qb, Kb, Vb, Ssum, zsum, vssum, nrm, vhb);
    gemm_bf16<1, 64><<<dim3(8, 32), 256, 0, stream>>>(vhb, Wob, out, nullptr, bo, nullptr, 2048, 1024, 1024);
}